// Round 1
// 1546.286 us; speedup vs baseline: 1.4187x; 1.4187x over previous
//
#include <hip/hip_runtime.h>
#include <math.h>

// Problem constants
#define B_    8
#define S_    4096
#define T_    77
#define C_    1280
#define CENC_ 2048
#define H_    20
#define D_    64
#define HD_   1280
#define M1_   (B_*S_)     // 32768 rows for Q / O GEMMs
#define MKV_  (B_*T_)     // 616 rows for K/V GEMM
#define KTOK_ 12          // ceil(77*0.15)
#define KPOS_ 1229        // ceil(4096*0.3)
#define SCALE_ 0.125f     // 1/sqrt(64)
#define CMIX_  0.15f      // STRENGTH*(1-ALPHA)
#define CINJ_  (0.25f/7.0f) // FIW*STRENGTH/(B-1)

typedef __attribute__((ext_vector_type(8))) short bf16x8;
typedef __attribute__((ext_vector_type(4))) float f32x4;

#define AS_G __attribute__((address_space(1)))
#define AS_L __attribute__((address_space(3)))
#define MFMA16 __builtin_amdgcn_mfma_f32_16x16x32_bf16

// ---------------------------------------------------------------------------
// bf16 helpers (RNE)
// ---------------------------------------------------------------------------
__device__ inline unsigned short f2bf(float x)
{
    union { float f; unsigned u; } v; v.f = x;
    const unsigned r = v.u + 0x7FFFu + ((v.u >> 16) & 1u);
    return (unsigned short)(r >> 16);
}
__device__ inline float bf2f(unsigned short h)
{
    union { float f; unsigned u; } v; v.u = ((unsigned)h) << 16;
    return v.f;
}

// split 8 consecutive fp32 -> bf16 hi + lo fragments (two aligned float4s)
__device__ inline void split_frag(const float* __restrict__ p, bf16x8& hi, bf16x8& lo)
{
    const float4 a = *(const float4*)p;
    const float4 b = *(const float4*)(p + 4);
    float f[8] = {a.x, a.y, a.z, a.w, b.x, b.y, b.z, b.w};
    #pragma unroll
    for (int e = 0; e < 8; ++e) {
        const unsigned short h = f2bf(f[e]);
        hi[e] = (short)h;
        lo[e] = (short)f2bf(f[e] - bf2f(h));
    }
}

// ---------------------------------------------------------------------------
// Split fp32 -> bf16 hi + bf16 lo (residual). One float4 per thread.
// ---------------------------------------------------------------------------
__global__ __launch_bounds__(256)
void split_convert_kernel(const float* __restrict__ x, unsigned short* __restrict__ hi,
                          unsigned short* __restrict__ lo)
{
    const size_t i4 = (size_t)blockIdx.x * 256 + threadIdx.x;
    const float4 v = ((const float4*)x)[i4];
    ushort4 h, l;
    h.x = f2bf(v.x); l.x = f2bf(v.x - bf2f(h.x));
    h.y = f2bf(v.y); l.y = f2bf(v.y - bf2f(h.y));
    h.z = f2bf(v.z); l.z = f2bf(v.z - bf2f(h.z));
    h.w = f2bf(v.w); l.w = f2bf(v.w - bf2f(h.w));
    ((ushort4*)hi)[i4] = h;
    ((ushort4*)lo)[i4] = l;
}

// ---------------------------------------------------------------------------
// Weight transpose + split: W[K=1280][N=1280] fp32 -> Thi/Tlo [N][K] bf16.
// ---------------------------------------------------------------------------
__global__ __launch_bounds__(256)
void wsplitT_kernel(const float* __restrict__ W, unsigned short* __restrict__ Thi,
                    unsigned short* __restrict__ Tlo)
{
    __shared__ float tile[32][33];
    const int tx = threadIdx.x & 31, ty = threadIdx.x >> 5;
    const int n0 = blockIdx.x * 32, k0 = blockIdx.y * 32;
    #pragma unroll
    for (int i = 0; i < 4; ++i) {
        const int kk = ty + i * 8;
        tile[kk][tx] = W[(size_t)(k0 + kk) * 1280 + n0 + tx];
    }
    __syncthreads();
    #pragma unroll
    for (int i = 0; i < 4; ++i) {
        const int nn = ty + i * 8;
        const float v = tile[tx][nn];               // = W[k0+tx][n0+nn]
        const unsigned short h = f2bf(v);
        const size_t oi = (size_t)(n0 + nn) * 1280 + k0 + tx;
        Thi[oi] = h;
        Tlo[oi] = f2bf(v - bf2f(h));
    }
}

// ---------------------------------------------------------------------------
// Injection + fp32->bf16 for the O-projection A operand:
// a = ctx*(1-8*cf) + cf*csum, cf = posm[row]*CINJ_.
// ---------------------------------------------------------------------------
__global__ __launch_bounds__(256)
void inject_convert_kernel(const float* __restrict__ ctx, const float* __restrict__ csum,
                           const float* __restrict__ posm, unsigned short* __restrict__ outb)
{
    const size_t i4 = (size_t)blockIdx.x * 256 + threadIdx.x;   // float4 index
    const int row = (int)(i4 / 320);
    const int c4  = (int)(i4 % 320);
    const float cf = posm[row] * CINJ_;
    const float am = 1.0f - 8.0f * cf;
    const float4 c  = ((const float4*)ctx)[i4];
    const float4 cs = ((const float4*)csum)[(size_t)(row & (S_ - 1)) * 320 + c4];
    ushort4 h;
    h.x = f2bf(c.x * am + cf * cs.x);
    h.y = f2bf(c.y * am + cf * cs.y);
    h.z = f2bf(c.z * am + cf * cs.z);
    h.w = f2bf(c.w * am + cf * cs.w);
    ((ushort4*)outb)[i4] = h;
}

// ---------------------------------------------------------------------------
// MFMA GEMM: C[M x 1280] = A[M x K] * B[K x 1280], A and B^T given in bf16.
// 128x128 tile, BK=32, 4 waves (2x2 of 64x64), 16x16x32 bf16 MFMA.
// SPLIT: acc += Ah*Bh + Ah*Bl + Al*Bh (fp32-ish accuracy).
// ---------------------------------------------------------------------------
__device__ inline void stage_tile(const unsigned short* __restrict__ gsrc,
                                  unsigned short* lds, int tid, int ldK,
                                  int row0, int k0)
{
    #pragma unroll
    for (int c0 = 0; c0 < 512; c0 += 256) {
        const int c = c0 + tid;
        const unsigned short* gp = gsrc + (size_t)(row0 + (c >> 2)) * ldK + k0 + (c & 3) * 8;
        __builtin_amdgcn_global_load_lds((const AS_G void*)gp, (AS_L void*)(lds + (size_t)c * 8),
                                         16, 0, 0);
    }
}

template<bool SPLIT, bool FUSE_OUT>
__global__ __launch_bounds__(256)
void mfma_gemm_kernel(const unsigned short* __restrict__ Ahi, const unsigned short* __restrict__ Alo,
                      const unsigned short* __restrict__ BhiT, const unsigned short* __restrict__ BloT,
                      float* __restrict__ Cout, int K,
                      const float* __restrict__ bias, const float* __restrict__ resid)
{
    __shared__ unsigned short sAhi[128 * 32];
    __shared__ unsigned short sBhi[128 * 32];
    __shared__ unsigned short sAlo[SPLIT ? 128 * 32 : 8];
    __shared__ unsigned short sBlo[SPLIT ? 128 * 32 : 8];

    const int tid  = threadIdx.x;
    const int lane = tid & 63;
    const int wave = tid >> 6;
    const int quad = lane >> 4;
    const int lrow = lane & 15;
    const int wm = (wave & 1) * 64;
    const int wn = (wave >> 1) * 64;

    // L2 panel swizzle: panel = 32 m-tiles; within panel m fastest, n slow.
    const int bid = blockIdx.x;
    const int panel = bid / 320;
    const int r = bid % 320;
    const int n0 = (r >> 5) * 128;
    const int m0 = (panel * 32 + (r & 31)) * 128;

    f32x4 acc[4][4] = {};

    for (int k0 = 0; k0 < K; k0 += 32) {
        __syncthreads();
        stage_tile(Ahi,  sAhi, tid, K, m0, k0);
        stage_tile(BhiT, sBhi, tid, K, n0, k0);
        if constexpr (SPLIT) {
            stage_tile(Alo,  sAlo, tid, K, m0, k0);
            stage_tile(BloT, sBlo, tid, K, n0, k0);
        }
        __syncthreads();

        bf16x8 ah[4], bh[4];
        #pragma unroll
        for (int i = 0; i < 4; ++i) {
            ah[i] = *(const bf16x8*)(sAhi + (wm + i * 16 + lrow) * 32 + quad * 8);
            bh[i] = *(const bf16x8*)(sBhi + (wn + i * 16 + lrow) * 32 + quad * 8);
        }
        if constexpr (SPLIT) {
            bf16x8 al[4], bl[4];
            #pragma unroll
            for (int i = 0; i < 4; ++i) {
                al[i] = *(const bf16x8*)(sAlo + (wm + i * 16 + lrow) * 32 + quad * 8);
                bl[i] = *(const bf16x8*)(sBlo + (wn + i * 16 + lrow) * 32 + quad * 8);
            }
            #pragma unroll
            for (int mt = 0; mt < 4; ++mt)
                #pragma unroll
                for (int nt = 0; nt < 4; ++nt) {
                    acc[mt][nt] = MFMA16(ah[mt], bh[nt], acc[mt][nt], 0, 0, 0);
                    acc[mt][nt] = MFMA16(ah[mt], bl[nt], acc[mt][nt], 0, 0, 0);
                    acc[mt][nt] = MFMA16(al[mt], bh[nt], acc[mt][nt], 0, 0, 0);
                }
        } else {
            #pragma unroll
            for (int mt = 0; mt < 4; ++mt)
                #pragma unroll
                for (int nt = 0; nt < 4; ++nt)
                    acc[mt][nt] = MFMA16(ah[mt], bh[nt], acc[mt][nt], 0, 0, 0);
        }
    }

    // Epilogue: C/D layout col = lane&15, row = quad*4 + reg (m89/m91-verified)
    #pragma unroll
    for (int mt = 0; mt < 4; ++mt) {
        #pragma unroll
        for (int nt = 0; nt < 4; ++nt) {
            const int col = n0 + wn + nt * 16 + lrow;
            #pragma unroll
            for (int r2 = 0; r2 < 4; ++r2) {
                const int row = m0 + wm + mt * 16 + quad * 4 + r2;
                float v = acc[mt][nt][r2];
                if constexpr (FUSE_OUT)
                    v += bias[col] + resid[(size_t)row * 1280 + col];
                Cout[(size_t)row * 1280 + col] = v;
            }
        }
    }
}

// ---------------------------------------------------------------------------
// fp32 GEMM, 64x64 tile, BK=16, 256 threads, 4x4 micro-tile. For K/V
// projections (M=616, K=2048, N=1280) — stays fp32 (feeds scoring path).
// ---------------------------------------------------------------------------
__global__ __launch_bounds__(256)
void gemm64_kernel(const float* __restrict__ A,
                   const float* __restrict__ B0, const float* __restrict__ B1,
                   float* __restrict__ C0, float* __restrict__ C1,
                   int M, int N, int K)
{
    const float* Bm = blockIdx.z ? B1 : B0;
    float* Cout = blockIdx.z ? C1 : C0;
    __shared__ float As[16][64];
    __shared__ float Bs[16][64];
    const int tid = threadIdx.x;
    const int n0 = blockIdx.x * 64;
    const int m0 = blockIdx.y * 64;
    const int tx = tid & 15, ty = tid >> 4;
    const int ar = tid >> 2;
    const int ak = (tid & 3) << 2;
    const int bk = tid >> 4;
    const int bn = (tid & 15) << 2;

    float acc[4][4] = {};
    const int arow = m0 + ar;
    const bool avalid = arow < M;
    const float* Ap = A + (size_t)arow * K + ak;
    const float* Bp = Bm + (size_t)bk * N + n0 + bn;

    for (int k0 = 0; k0 < K; k0 += 16) {
        const float4 a = avalid ? *(const float4*)(Ap + k0) : make_float4(0.f,0.f,0.f,0.f);
        const float4 b = *(const float4*)(Bp + (size_t)k0 * N);
        __syncthreads();
        As[ak+0][ar] = a.x; As[ak+1][ar] = a.y; As[ak+2][ar] = a.z; As[ak+3][ar] = a.w;
        *(float4*)&Bs[bk][bn] = b;
        __syncthreads();
        #pragma unroll
        for (int kk = 0; kk < 16; ++kk) {
            const float4 av = *(const float4*)&As[kk][ty*4];
            const float4 bv = *(const float4*)&Bs[kk][tx*4];
            const float arr[4] = {av.x, av.y, av.z, av.w};
            const float brr[4] = {bv.x, bv.y, bv.z, bv.w};
            #pragma unroll
            for (int r = 0; r < 4; ++r)
                #pragma unroll
                for (int c = 0; c < 4; ++c)
                    acc[r][c] = fmaf(arr[r], brr[c], acc[r][c]);
        }
    }
    #pragma unroll
    for (int r = 0; r < 4; ++r) {
        const int row = m0 + ty * 4 + r;
        if (row < M) {
            const float4 cv = make_float4(acc[r][0], acc[r][1], acc[r][2], acc[r][3]);
            *(float4*)(Cout + (size_t)row * N + n0 + tx * 4) = cv;
        }
    }
}

__device__ inline bool first_pair(float va, int ia, float vb, int ib)
{
    return (va > vb) || (va == vb && ia < ib);
}

// descending by (value, then index asc) — matches lax.top_k tie-break
__device__ inline void bitonic_desc(float* vals, int* idxs, int n, int tid, int nt)
{
    for (int k = 2; k <= n; k <<= 1) {
        for (int j = k >> 1; j > 0; j >>= 1) {
            __syncthreads();
            for (int i = tid; i < n; i += nt) {
                const int l = i ^ j;
                if (l > i) {
                    const float vi = vals[i], vl = vals[l];
                    const int   ii = idxs[i], il = idxs[l];
                    const bool up = (i & k) == 0;
                    const bool sw = up ? first_pair(vl, il, vi, ii)
                                       : first_pair(vi, ii, vl, il);
                    if (sw) { vals[i] = vl; vals[l] = vi; idxs[i] = il; idxs[l] = ii; }
                }
            }
        }
    }
    __syncthreads();
}

// ---------------------------------------------------------------------------
// Pass A (MFMA): swapped QK^T -> per-lane logits for 16 s-cols (s = lane&15),
// t = nt*16 + quad*4 + r. 4-product split bf16 QK (fp32-level accuracy; the
// logits feed the top-k masks, which must not flip). Softmax over t = register
// max/sum + shfl_xor(16/32) quad reduce. Accumulate sum_s p per t -> tokp.
// Grid: 2560 blocks = b(8) x h(20) x s-chunk(16); 4 waves x 4 s-tiles = 256 s.
// ---------------------------------------------------------------------------
__global__ __launch_bounds__(256)
void pass_a_kernel(const float* __restrict__ q, const float* __restrict__ kbuf,
                   float* __restrict__ tokp)
{
    __shared__ unsigned short khi[80 * 64];   // [t][d] bf16, XOR-swizzled rows
    __shared__ unsigned short klo[80 * 64];
    __shared__ float wsum[4][80];
    const int g = blockIdx.x;
    const int b = g / 320;
    const int rem = g % 320;
    const int h = rem >> 4;
    const int chunk = rem & 15;
    const int tid = threadIdx.x;

    // stage K slice -> swizzled bf16 hi/lo (T2 swizzle: byte ^= (t&7)<<4)
    for (int i = tid; i < 80 * 16; i += 256) {
        const int t = i >> 4, j = i & 15;                 // d0 = 4*j
        float4 v = make_float4(0.f, 0.f, 0.f, 0.f);
        if (t < T_) v = *(const float4*)(kbuf + (size_t)(b * T_ + t) * HD_ + h * D_ + 4 * j);
        ushort4 hh, ll;
        hh.x = f2bf(v.x); ll.x = f2bf(v.x - bf2f(hh.x));
        hh.y = f2bf(v.y); ll.y = f2bf(v.y - bf2f(hh.y));
        hh.z = f2bf(v.z); ll.z = f2bf(v.z - bf2f(hh.z));
        hh.w = f2bf(v.w); ll.w = f2bf(v.w - bf2f(hh.w));
        const int byt = t * 128 + ((8 * j) ^ ((t & 7) << 4));
        *(ushort4*)((char*)khi + byt) = hh;
        *(ushort4*)((char*)klo + byt) = ll;
    }
    __syncthreads();

    const int wid = tid >> 6, lane = tid & 63;
    const int lrow = lane & 15, quad = lane >> 4;

    f32x4 tokacc[5] = {};
    for (int st = 0; st < 4; ++st) {
        const int s = chunk * 256 + wid * 64 + st * 16 + lrow;
        const float* qp = q + (size_t)(b * S_ + s) * HD_ + h * D_;
        bf16x8 qhi[2], qlo[2];
        #pragma unroll
        for (int ks = 0; ks < 2; ++ks)
            split_frag(qp + ks * 32 + quad * 8, qhi[ks], qlo[ks]);

        f32x4 acc[5] = {};
        #pragma unroll
        for (int nt = 0; nt < 5; ++nt) {
            #pragma unroll
            for (int ks = 0; ks < 2; ++ks) {
                const int krow = nt * 16 + lrow;
                const int byt = krow * 128 + ((64 * ks + 16 * quad) ^ ((krow & 7) << 4));
                const bf16x8 kh = *(const bf16x8*)((const char*)khi + byt);
                const bf16x8 kl = *(const bf16x8*)((const char*)klo + byt);
                acc[nt] = MFMA16(kh, qhi[ks], acc[nt], 0, 0, 0);
                acc[nt] = MFMA16(kh, qlo[ks], acc[nt], 0, 0, 0);
                acc[nt] = MFMA16(kl, qhi[ks], acc[nt], 0, 0, 0);
                acc[nt] = MFMA16(kl, qlo[ks], acc[nt], 0, 0, 0);
            }
        }
        float m = -1e30f;
        #pragma unroll
        for (int nt = 0; nt < 5; ++nt)
            #pragma unroll
            for (int r = 0; r < 4; ++r) {
                const int t = nt * 16 + quad * 4 + r;
                const float l = (t < T_) ? acc[nt][r] * SCALE_ : -1e30f;
                acc[nt][r] = l;
                m = fmaxf(m, l);
            }
        m = fmaxf(m, __shfl_xor(m, 16, 64));
        m = fmaxf(m, __shfl_xor(m, 32, 64));
        float Lp = 0.f;
        #pragma unroll
        for (int nt = 0; nt < 5; ++nt)
            #pragma unroll
            for (int r = 0; r < 4; ++r) {
                const float e = __expf(acc[nt][r] - m);
                acc[nt][r] = e;
                Lp += e;
            }
        float L = Lp + __shfl_xor(Lp, 16, 64);
        L += __shfl_xor(L, 32, 64);
        const float invL = 1.0f / L;
        #pragma unroll
        for (int nt = 0; nt < 5; ++nt)
            #pragma unroll
            for (int r = 0; r < 4; ++r)
                tokacc[nt][r] = fmaf(acc[nt][r], invL, tokacc[nt][r]);
    }
    // reduce over the 16 s-columns (lane bits 0..3), write per-wave partials
    #pragma unroll
    for (int nt = 0; nt < 5; ++nt)
        #pragma unroll
        for (int r = 0; r < 4; ++r) {
            float v = tokacc[nt][r];
            v += __shfl_xor(v, 1, 64);
            v += __shfl_xor(v, 2, 64);
            v += __shfl_xor(v, 4, 64);
            v += __shfl_xor(v, 8, 64);
            if (lrow == 0) wsum[wid][nt * 16 + quad * 4 + r] = v;
        }
    __syncthreads();
    for (int t = tid; t < T_; t += 256)
        tokp[(size_t)g * T_ + t] = (wsum[0][t] + wsum[1][t]) + (wsum[2][t] + wsum[3][t]);
}

// ---------------------------------------------------------------------------
// Top-k over 77 token scores per batch -> tok_mask. 8 blocks x 128 threads.
// ---------------------------------------------------------------------------
__global__ __launch_bounds__(128)
void topk_tok_kernel(const float* __restrict__ tokp, float* __restrict__ tokm)
{
    __shared__ float vals[128];
    __shared__ int idxs[128];
    const int b = blockIdx.x, tid = threadIdx.x;
    float v = -1e30f;
    if (tid < T_) {
        float sm = 0.f;
        for (int j = 0; j < 320; ++j) sm += tokp[(size_t)(b * 320 + j) * T_ + tid];
        v = sm;
    }
    vals[tid] = v; idxs[tid] = tid;
    bitonic_desc(vals, idxs, 128, tid, 128);
    if (tid < T_) tokm[b * T_ + tid] = 0.f;
    __syncthreads();
    if (tid < KTOK_) tokm[b * T_ + idxs[tid]] = 1.0f;
}

// ---------------------------------------------------------------------------
// K/V cross-frame mixing: kd = k2-k (delta, mask folded in), v2 = mixed v.
// ---------------------------------------------------------------------------
__global__ __launch_bounds__(256)
void mix_kernel(const float* __restrict__ kbuf, const float* __restrict__ vbuf,
                const float* __restrict__ tokm,
                float* __restrict__ kd, float* __restrict__ v2)
{
    const int i = blockIdx.x * 256 + threadIdx.x;   // < 77*1280 = 98560
    const int t = i / HD_;
    float ks = 0.f, vs = 0.f;
    #pragma unroll
    for (int b = 0; b < B_; ++b) {
        ks += kbuf[(size_t)b * T_ * HD_ + i];
        vs += vbuf[(size_t)b * T_ * HD_ + i];
    }
    #pragma unroll
    for (int b = 0; b < B_; ++b) {
        const size_t gi = (size_t)b * T_ * HD_ + i;
        const float msk = tokm[b * T_ + t];
        const float kx = kbuf[gi], vx = vbuf[gi];
        kd[gi] = CMIX_ * msk * ((ks - 8.f * kx) * (1.0f / 7.0f));
        v2[gi] = vx + CMIX_ * msk * ((vs - 8.f * vx) * (1.0f / 7.0f));
    }
}

// ---------------------------------------------------------------------------
// Fused pass B+C (MFMA): swapped QK^T gives per-lane l1 (split, 4 products)
// and l2 = l1 + q·kd (kd bf16-hi; mask folded into kd). Register softmax for
// both; posp = masked mass of softmax(l1); p2 = softmax(l2) -> LDS round-trip
// per 32-wide k-step (hi/lo) -> swapped PV mfma(V^T, P) -> ctx.
// ---------------------------------------------------------------------------
__global__ __launch_bounds__(256)
void pass_bc_kernel(const float* __restrict__ q, const float* __restrict__ kbuf,
                    const float* __restrict__ kd, const float* __restrict__ v2,
                    const float* __restrict__ tokm,
                    float* __restrict__ posp, float* __restrict__ ctx)
{
    __shared__ unsigned short khi[80 * 64];     // [t][d] XOR-swizzled
    __shared__ unsigned short klo[80 * 64];
    __shared__ unsigned short kdh[80 * 64];
    __shared__ unsigned short vThi[64 * 88];    // [d][t] rows padded to 88
    __shared__ unsigned short vTlo[64 * 88];
    __shared__ unsigned short vguard[128];      // zeroed guard for vT overreads
    __shared__ unsigned short Pbuf[4][2][16 * 40]; // per-wave [hi/lo][s][tloc]
    __shared__ float smaskf[80];

    const int g = blockIdx.x;
    const int b = g / 320;
    const int rem = g % 320;
    const int h = rem >> 4;
    const int chunk = rem & 15;
    const int tid = threadIdx.x;

    // ---- stage K (hi/lo) + Kd (hi), swizzled ----
    for (int i = tid; i < 80 * 16; i += 256) {
        const int t = i >> 4, j = i & 15;
        float4 vk = make_float4(0.f, 0.f, 0.f, 0.f);
        float4 vd = make_float4(0.f, 0.f, 0.f, 0.f);
        if (t < T_) {
            const size_t gi = (size_t)(b * T_ + t) * HD_ + h * D_ + 4 * j;
            vk = *(const float4*)(kbuf + gi);
            vd = *(const float4*)(kd + gi);
        }
        ushort4 hh, ll, dd;
        hh.x = f2bf(vk.x); ll.x = f2bf(vk.x - bf2f(hh.x)); dd.x = f2bf(vd.x);
        hh.y = f2bf(vk.y); ll.y = f2bf(vk.y - bf2f(hh.y)); dd.y = f2bf(vd.y);
        hh.z = f2bf(vk.z); ll.z = f2bf(vk.z - bf2f(hh.z)); dd.z = f2bf(vd.z);
        hh.w = f2bf(vk.w); ll.w = f2bf(vk.w - bf2f(hh.w)); dd.w = f2bf(vd.w);
        const int byt = t * 128 + ((8 * j) ^ ((t & 7) << 4));
        *(ushort4*)((char*)khi + byt) = hh;
        *(ushort4*)((char*)klo + byt) = ll;
        *(ushort4*)((char*)kdh + byt) = dd;
    }
    // ---- stage V^T (hi/lo): rows d (88 cols, zero-padded past t=76) ----
    for (int i = tid; i < 64 * 22; i += 256) {
        const int d = i / 22, jg = i - d * 22;           // cols t = 4*jg..+3
        float vv[4];
        #pragma unroll
        for (int r = 0; r < 4; ++r) {
            const int t = 4 * jg + r;
            vv[r] = (t < T_) ? v2[(size_t)(b * T_ + t) * HD_ + h * D_ + d] : 0.f;
        }
        ushort4 hh, ll;
        hh.x = f2bf(vv[0]); ll.x = f2bf(vv[0] - bf2f(hh.x));
        hh.y = f2bf(vv[1]); ll.y = f2bf(vv[1] - bf2f(hh.y));
        hh.z = f2bf(vv[2]); ll.z = f2bf(vv[2] - bf2f(hh.z));
        hh.w = f2bf(vv[3]); ll.w = f2bf(vv[3] - bf2f(hh.w));
        const int byt = d * 176 + 8 * jg;
        *(ushort4*)((char*)vThi + byt) = hh;
        *(ushort4*)((char*)vTlo + byt) = ll;
    }
    for (int t = tid; t < 80; t += 256) smaskf[t] = (t < T_) ? tokm[b * T_ + t] : 0.f;
    for (int i = tid; i < 128; i += 256) vguard[i] = 0;
    __syncthreads();

    const int wid = tid >> 6, lane = tid & 63;
    const int lrow = lane & 15, quad = lane >> 4;
    unsigned short* Ph = &Pbuf[wid][0][0];
    unsigned short* Pl = &Pbuf[wid][1][0];

    // hoist per-lane token-mask values (constant across s-tiles)
    float smv[5][4];
    #pragma unroll
    for (int nt = 0; nt < 5; ++nt)
        #pragma unroll
        for (int r = 0; r < 4; ++r)
            smv[nt][r] = smaskf[nt * 16 + quad * 4 + r];

    for (int st = 0; st < 4; ++st) {
        const int s = chunk * 256 + wid * 64 + st * 16 + lrow;
        const float* qp = q + (size_t)(b * S_ + s) * HD_ + h * D_;
        bf16x8 qhi[2], qlo[2];
        #pragma unroll
        for (int ks = 0; ks < 2; ++ks)
            split_frag(qp + ks * 32 + quad * 8, qhi[ks], qlo[ks]);

        f32x4 acc1[5] = {}, accd[5] = {};
        #pragma unroll
        for (int nt = 0; nt < 5; ++nt) {
            #pragma unroll
            for (int ks = 0; ks < 2; ++ks) {
                const int krow = nt * 16 + lrow;
                const int byt = krow * 128 + ((64 * ks + 16 * quad) ^ ((krow & 7) << 4));
                const bf16x8 kh = *(const bf16x8*)((const char*)khi + byt);
                const bf16x8 kl = *(const bf16x8*)((const char*)klo + byt);
                const bf16x8 kdv = *(const bf16x8*)((const char*)kdh + byt);
                acc1[nt] = MFMA16(kh, qhi[ks], acc1[nt], 0, 0, 0);
                acc1[nt] = MFMA16(kh, qlo[ks], acc1[nt], 0, 0, 0);
                acc1[nt] = MFMA16(kl, qhi[ks], acc1[nt], 0, 0, 0);
                acc1[nt] = MFMA16(kl, qlo[ks], acc1[nt], 0, 0, 0);
                accd[nt] = MFMA16(kdv, qhi[ks], accd[nt], 0, 0, 0);
            }
        }

        // logits + dual softmax (l1: pos score; l2: second attention)
        float m1 = -1e30f, m2 = -1e30f;
        f32x4 l2v[5];
        #pragma unroll
        for (int nt = 0; nt < 5; ++nt)
            #pragma unroll
            for (int r = 0; r < 4; ++r) {
                const int t = nt * 16 + quad * 4 + r;
                const bool valid = t < T_;
                const float l1 = valid ? acc1[nt][r] * SCALE_ : -1e30f;
                const float l2 = valid ? l1 + accd[nt][r] * SCALE_ : -1e30f;
                acc1[nt][r] = l1;
                l2v[nt][r] = l2;
                m1 = fmaxf(m1, l1);
                m2 = fmaxf(m2, l2);
            }
        m1 = fmaxf(m1, __shfl_xor(m1, 16, 64));
        m1 = fmaxf(m1, __shfl_xor(m1, 32, 64));
        m2 = fmaxf(m2, __shfl_xor(m2, 16, 64));
        m2 = fmaxf(m2, __shfl_xor(m2, 32, 64));
        float L1p = 0.f, Smp = 0.f, L2p = 0.f;
        #pragma unroll
        for (int nt = 0; nt < 5; ++nt)
            #pragma unroll
            for (int r = 0; r < 4; ++r) {
                const float e1 = __expf(acc1[nt][r] - m1);
                L1p += e1;
                Smp = fmaf(e1, smv[nt][r], Smp);
                const float e2 = __expf(l2v[nt][r] - m2);
                l2v[nt][r] = e2;
                L2p += e2;
            }
        float L1 = L1p + __shfl_xor(L1p, 16, 64); L1 += __shfl_xor(L1, 32, 64);
        float Sm = Smp + __shfl_xor(Smp, 16, 64); Sm += __shfl_xor(Sm, 32, 64);
        float L2 = L2p + __shfl_xor(L2p, 16, 64); L2 += __shfl_xor(L2, 32, 64);
        if (quad == 0) posp[(size_t)(b * H_ + h) * S_ + s] = Sm / L1;
        const float invL2 = 1.0f / L2;
        #pragma unroll
        for (int nt = 0; nt < 5; ++nt)
            #pragma unroll
            for (int r = 0; r < 4; ++r)
                l2v[nt][r] *= invL2;

        // PV: per 32-wide k-step, P -> LDS (hi/lo) -> B-frags, V^T A-frags
        f32x4 pv[4] = {};
        #pragma unroll
        for (int ks = 0; ks < 3; ++ks) {
            asm volatile("s_waitcnt lgkmcnt(0)" ::: "memory");
            __builtin_amdgcn_sched_barrier(0);
            #pragma unroll
            for (int half = 0; half < 2; ++half) {
                const int nt = 2 * ks + half;
                ushort4 ph = {0, 0, 0, 0}, plw = {0, 0, 0, 0};
                if (nt < 5) {
                    ph.x = f2bf(l2v[nt][0]); plw.x = f2bf(l2v[nt][0] - bf2f(ph.x));
                    ph.y = f2bf(l2v[nt][1]); plw.y = f2bf(l2v[nt][1] - bf2f(ph.y));
                    ph.z = f2bf(l2v[nt][2]); plw.z = f2bf(l2v[nt][2] - bf2f(ph.z));
                    ph.w = f2bf(l2v[nt][3]); plw.w = f2bf(l2v[nt][3] - bf2f(ph.w));
                }
                const int pb = lrow * 80 + 32 * half + 8 * quad;
                *(ushort4*)((char*)Ph + pb) = ph;
                *(ushort4*)((char*)Pl + pb) = plw;
            }
            asm volatile("s_waitcnt lgkmcnt(0)" ::: "memory");
            __builtin_amdgcn_sched_barrier(0);
            const bf16x8 pH = *(const bf16x8*)((const char*)Ph + lrow * 80 + quad * 16);
            const bf16x8 pL = *(const bf16x8*)((const char*)Pl + lrow * 80 + quad * 16);
            #pragma unroll
            for (int mt = 0; mt < 4; ++mt) {
                const int vb = (mt * 16 + lrow) * 176 + 64 * ks + 16 * quad;
                const bf16x8 vH = *(const bf16x8*)((const char*)vThi + vb);
                const bf16x8 vL = *(const bf16x8*)((const char*)vTlo + vb);
                pv[mt] = MFMA16(vH, pH, pv[mt], 0, 0, 0);
                pv[mt] = MFMA16(vH, pL, pv[mt], 0, 0, 0);
                pv[mt] = MFMA16(vL, pH, pv[mt], 0, 0, 0);
            }
        }
        // ctx write: col = lane&15 = s, row(d) = mt*16 + quad*4 + reg
        float* cp = ctx + (size_t)(b * S_ + s) * HD_ + h * D_;
        #pragma unroll
        for (int mt = 0; mt < 4; ++mt) {
            const float4 o = make_float4(pv[mt][0], pv[mt][1], pv[mt][2], pv[mt][3]);
            *(float4*)(cp + mt * 16 + quad * 4) = o;
        }
    }
}

// ---------------------------------------------------------------------------
// Top-k over 4096 position scores per batch -> pos_mask. 8 blocks x 1024.
// ---------------------------------------------------------------------------
__global__ __launch_bounds__(1024)
void topk_pos_kernel(const float* __restrict__ posp, float* __restrict__ posm)
{
    __shared__ float vals[S_];
    __shared__ int idxs[S_];
    const int b = blockIdx.x, tid = threadIdx.x;
    for (int s = tid; s < S_; s += 1024) {
        float sm = 0.f;
        for (int h = 0; h < H_; ++h) sm += posp[(size_t)(b * H_ + h) * S_ + s];
        vals[s] = sm; idxs[s] = s;
    }
    bitonic_desc(vals, idxs, S_, tid, 1024);
    for (int s = tid; s < S_; s += 1024) posm[b * S_ + s] = 0.f;
    __syncthreads();
    for (int i = tid; i < KPOS_; i += 1024) posm[b * S_ + idxs[i]] = 1.0f;
}

// ---------------------------------------------------------------------------
// Batch-sum of context over b: csum[s,hd] = sum_b ctx[b,s,hd]. float4 lanes.
// ---------------------------------------------------------------------------
__global__ __launch_bounds__(256)
void ctxsum_kernel(const float* __restrict__ ctx, float* __restrict__ csum)
{
    const size_t i = (size_t)blockIdx.x * 256 + threadIdx.x;  // float4 index
    const float4* c = (const float4*)ctx;
    float4 a = c[i];
    #pragma unroll
    for (int b = 1; b < B_; ++b) {
        const float4 x = c[(size_t)b * (S_ * HD_ / 4) + i];
        a.x += x.x; a.y += x.y; a.z += x.z; a.w += x.w;
    }
    ((float4*)csum)[i] = a;
}

// ---------------------------------------------------------------------------
extern "C" void kernel_launch(void* const* d_in, const int* in_sizes, int n_in,
                              void* d_out, int out_size, void* d_ws, size_t ws_size,
                              hipStream_t stream)
{
    const float* hidden = (const float*)d_in[0];
    const float* enc    = (const float*)d_in[1];
    const float* Wq     = (const float*)d_in[2];
    const float* Wk     = (const float*)d_in[3];
    const float* Wv     = (const float*)d_in[4];
    const float* Wo     = (const float*)d_in[5];
    const float* bo     = (const float*)d_in[6];
    float* out = (float*)d_out;

    char* w = (char*)d_ws;
    float* q    = (float*)w; w += (size_t)M1_ * HD_ * 4;
    float* ctx  = (float*)w; w += (size_t)M1_ * HD_ * 4;
    float* kbuf = (float*)w; w += (size_t)B_ * T_ * HD_ * 4;
    float* vbuf = (float*)w; w += (size_t)B_ * T_ * HD_ * 4;
    float* kd   = (float*)w; w += (size_t)B_ * T_ * HD_ * 4;
    float* v2   = (float*)w; w += (size_t)B_ * T_ * HD_ * 4;
    float* csum = (float*)w; w += (size_t)S_ * HD_ * 4;
    float* tokp = (float*)w; w += (size_t)2560 * T_ * 4;
    float* posp = (float*)w; w += (size_t)B_ * H_ * S_ * 4;
    float* tokm = (float*)w; w += (size_t)B_ * T_ * 4;
    float* posm = (float*)w; w += (size_t)B_ * S_ * 4;
    unsigned short* Ahi   = (unsigned short*)w; w += (size_t)M1_ * HD_ * 2;
    unsigned short* Alo   = (unsigned short*)w; w += (size_t)M1_ * HD_ * 2;
    unsigned short* ctxb  = (unsigned short*)w; w += (size_t)M1_ * HD_ * 2;
    unsigned short* WqhiT = (unsigned short*)w; w += (size_t)C_ * HD_ * 2;
    unsigned short* WqloT = (unsigned short*)w; w += (size_t)C_ * HD_ * 2;
    unsigned short* WohiT = (unsigned short*)w; w += (size_t)HD_ * C_ * 2;
    unsigned short* WoloT = (unsigned short*)w; w += (size_t)HD_ * C_ * 2;
    (void)ws_size; (void)in_sizes; (void)n_in; (void)out_size;

    // 1. Split hidden -> bf16 hi/lo; weights -> transposed bf16 hi/lo
    split_convert_kernel<<<M1_ * HD_ / 4 / 256, 256, 0, stream>>>(hidden, Ahi, Alo);
    wsplitT_kernel<<<dim3(40, 40), 256, 0, stream>>>(Wq, WqhiT, WqloT);
    wsplitT_kernel<<<dim3(40, 40), 256, 0, stream>>>(Wo, WohiT, WoloT);
    // 2. Q projection: split-bf16 MFMA (3 products ~ fp32 accuracy)
    mfma_gemm_kernel<true, false><<<2560, 256, 0, stream>>>(
        Ahi, Alo, WqhiT, WqloT, q, C_, nullptr, nullptr);
    // 3. K and V projections (fp32 — feeds scoring path)
    gemm64_kernel<<<dim3(20, 10, 2), 256, 0, stream>>>(
        enc, Wk, Wv, kbuf, vbuf, MKV_, HD_, CENC_);
    // 4. First attention (MFMA) -> token-score partials
    pass_a_kernel<<<2560, 256, 0, stream>>>(q, kbuf, tokp);
    // 5. Token top-k mask
    topk_tok_kernel<<<8, 128, 0, stream>>>(tokp, tokm);
    // 6. Cross-frame K/V mixing
    mix_kernel<<<385, 256, 0, stream>>>(kbuf, vbuf, tokm, kd, v2);
    // 7. Fused pass B (pos scores) + pass C (second attention, MFMA)
    pass_bc_kernel<<<2560, 256, 0, stream>>>(q, kbuf, kd, v2, tokm, posp, ctx);
    // 8. Position top-k mask
    topk_pos_kernel<<<8, 1024, 0, stream>>>(posp, posm);
    // 9. Batch-sum of context for mean-of-others injection
    ctxsum_kernel<<<S_ * HD_ / 4 / 256, 256, 0, stream>>>(ctx, csum);
    // 10. Injection + bf16 convert of context (A operand of O-proj)
    inject_convert_kernel<<<M1_ * HD_ / 4 / 256, 256, 0, stream>>>(ctx, csum, posm, ctxb);
    // 11. O projection: plain bf16 MFMA + bias + residual epilogue
    mfma_gemm_kernel<false, true><<<2560, 256, 0, stream>>>(
        ctxb, nullptr, WohiT, nullptr, out, HD_, bo, hidden);
}

// Round 2
// 1545.430 us; speedup vs baseline: 1.4195x; 1.0006x over previous
//
#include <hip/hip_runtime.h>
#include <math.h>

// Problem constants
#define B_    8
#define S_    4096
#define T_    77
#define C_    1280
#define CENC_ 2048
#define H_    20
#define D_    64
#define HD_   1280
#define M1_   (B_*S_)     // 32768 rows for Q / O GEMMs
#define MKV_  (B_*T_)     // 616 rows for K/V GEMM
#define KTOK_ 12          // ceil(77*0.15)
#define KPOS_ 1229        // ceil(4096*0.3)
#define SCALE_ 0.125f     // 1/sqrt(64)
#define CMIX_  0.15f      // STRENGTH*(1-ALPHA)
#define CINJ_  (0.25f/7.0f) // FIW*STRENGTH/(B-1)

typedef __attribute__((ext_vector_type(8))) short bf16x8;
typedef __attribute__((ext_vector_type(4))) float f32x4;

#define AS_G __attribute__((address_space(1)))
#define AS_L __attribute__((address_space(3)))
#define MFMA16 __builtin_amdgcn_mfma_f32_16x16x32_bf16

// ---------------------------------------------------------------------------
// bf16 helpers (RNE)
// ---------------------------------------------------------------------------
__device__ inline unsigned short f2bf(float x)
{
    union { float f; unsigned u; } v; v.f = x;
    const unsigned r = v.u + 0x7FFFu + ((v.u >> 16) & 1u);
    return (unsigned short)(r >> 16);
}
__device__ inline float bf2f(unsigned short h)
{
    union { float f; unsigned u; } v; v.u = ((unsigned)h) << 16;
    return v.f;
}

// split 8 consecutive fp32 -> bf16 hi + lo fragments (two aligned float4s)
__device__ inline void split_frag(const float* __restrict__ p, bf16x8& hi, bf16x8& lo)
{
    const float4 a = *(const float4*)p;
    const float4 b = *(const float4*)(p + 4);
    float f[8] = {a.x, a.y, a.z, a.w, b.x, b.y, b.z, b.w};
    #pragma unroll
    for (int e = 0; e < 8; ++e) {
        const unsigned short h = f2bf(f[e]);
        hi[e] = (short)h;
        lo[e] = (short)f2bf(f[e] - bf2f(h));
    }
}

// ---------------------------------------------------------------------------
// Split fp32 -> bf16 hi + bf16 lo (residual). One float4 per thread.
// ---------------------------------------------------------------------------
__global__ __launch_bounds__(256)
void split_convert_kernel(const float* __restrict__ x, unsigned short* __restrict__ hi,
                          unsigned short* __restrict__ lo)
{
    const size_t i4 = (size_t)blockIdx.x * 256 + threadIdx.x;
    const float4 v = ((const float4*)x)[i4];
    ushort4 h, l;
    h.x = f2bf(v.x); l.x = f2bf(v.x - bf2f(h.x));
    h.y = f2bf(v.y); l.y = f2bf(v.y - bf2f(h.y));
    h.z = f2bf(v.z); l.z = f2bf(v.z - bf2f(h.z));
    h.w = f2bf(v.w); l.w = f2bf(v.w - bf2f(h.w));
    ((ushort4*)hi)[i4] = h;
    ((ushort4*)lo)[i4] = l;
}

// ---------------------------------------------------------------------------
// Weight transpose + split: W[K=1280][N=1280] fp32 -> Thi/Tlo [N][K] bf16.
// ---------------------------------------------------------------------------
__global__ __launch_bounds__(256)
void wsplitT_kernel(const float* __restrict__ W, unsigned short* __restrict__ Thi,
                    unsigned short* __restrict__ Tlo)
{
    __shared__ float tile[32][33];
    const int tx = threadIdx.x & 31, ty = threadIdx.x >> 5;
    const int n0 = blockIdx.x * 32, k0 = blockIdx.y * 32;
    #pragma unroll
    for (int i = 0; i < 4; ++i) {
        const int kk = ty + i * 8;
        tile[kk][tx] = W[(size_t)(k0 + kk) * 1280 + n0 + tx];
    }
    __syncthreads();
    #pragma unroll
    for (int i = 0; i < 4; ++i) {
        const int nn = ty + i * 8;
        const float v = tile[tx][nn];               // = W[k0+tx][n0+nn]
        const unsigned short h = f2bf(v);
        const size_t oi = (size_t)(n0 + nn) * 1280 + k0 + tx;
        Thi[oi] = h;
        Tlo[oi] = f2bf(v - bf2f(h));
    }
}

// ---------------------------------------------------------------------------
// Injection + fp32->bf16 for the O-projection A operand:
// a = ctx*(1-8*cf) + cf*csum, cf = posm[row]*CINJ_.
// ---------------------------------------------------------------------------
__global__ __launch_bounds__(256)
void inject_convert_kernel(const float* __restrict__ ctx, const float* __restrict__ csum,
                           const float* __restrict__ posm, unsigned short* __restrict__ outb)
{
    const size_t i4 = (size_t)blockIdx.x * 256 + threadIdx.x;   // float4 index
    const int row = (int)(i4 / 320);
    const int c4  = (int)(i4 % 320);
    const float cf = posm[row] * CINJ_;
    const float am = 1.0f - 8.0f * cf;
    const float4 c  = ((const float4*)ctx)[i4];
    const float4 cs = ((const float4*)csum)[(size_t)(row & (S_ - 1)) * 320 + c4];
    ushort4 h;
    h.x = f2bf(c.x * am + cf * cs.x);
    h.y = f2bf(c.y * am + cf * cs.y);
    h.z = f2bf(c.z * am + cf * cs.z);
    h.w = f2bf(c.w * am + cf * cs.w);
    ((ushort4*)outb)[i4] = h;
}

// ---------------------------------------------------------------------------
// MFMA GEMM: C[M x 1280] = A[M x K] * B[K x 1280], A and B^T given in bf16.
// 128x128 tile, BK=32, 4 waves (2x2 of 64x64), 16x16x32 bf16 MFMA.
// SPLIT: acc += Ah*Bh + Ah*Bl + Al*Bh (fp32-ish accuracy).
//
// LDS layout (bank-conflict-free, r1): logical tile [128 rows][32 bf16]
// pair-packed into [64 prows][128 B]; within each 128-B prow the 8 16-B
// chunks are XOR-swizzled by (prow&7). global_load_lds keeps a LINEAR
// per-wave dest (base + lane*16) and the inverse permutation is applied
// to the per-lane GLOBAL source address (m173 pattern, rule #21).
// Read bank check (16 lanes, fixed quad): group = (row&1)*4 + (quad^(row>>1))
// mod 8 -> exactly 2 lanes/group = free (m136: 2-way is 1.02x).
// ---------------------------------------------------------------------------
__device__ inline void stage_tile(const unsigned short* __restrict__ gsrc,
                                  unsigned short* lds, int tid, int ldK,
                                  int row0, int k0)
{
    #pragma unroll
    for (int c0 = 0; c0 < 512; c0 += 256) {
        const int c = c0 + tid;                    // 16-B chunk index in LDS
        const int rr = c >> 3;                     // packed row (2 logical rows)
        const int l  = (c & 7) ^ (rr & 7);         // logical chunk (involution)
        const int row = 2 * rr + (l >> 2);         // logical tile row
        const int j   = l & 3;                     // 16-B k-chunk within row
        const unsigned short* gp = gsrc + (size_t)(row0 + row) * ldK + k0 + j * 8;
        __builtin_amdgcn_global_load_lds((const AS_G void*)gp, (AS_L void*)(lds + (size_t)c * 8),
                                         16, 0, 0);
    }
}

// swizzled read offset (in bytes) for logical (row, 16-B chunk quad)
__device__ inline int swz_off(int row, int quad)
{
    const int rr = row >> 1;
    const int pos = (((row & 1) << 2) | quad) ^ (rr & 7);
    return rr * 128 + pos * 16;
}

template<bool SPLIT, bool FUSE_OUT>
__global__ __launch_bounds__(256)
void mfma_gemm_kernel(const unsigned short* __restrict__ Ahi, const unsigned short* __restrict__ Alo,
                      const unsigned short* __restrict__ BhiT, const unsigned short* __restrict__ BloT,
                      float* __restrict__ Cout, int K,
                      const float* __restrict__ bias, const float* __restrict__ resid)
{
    __shared__ unsigned short sAhi[128 * 32];
    __shared__ unsigned short sBhi[128 * 32];
    __shared__ unsigned short sAlo[SPLIT ? 128 * 32 : 8];
    __shared__ unsigned short sBlo[SPLIT ? 128 * 32 : 8];

    const int tid  = threadIdx.x;
    const int lane = tid & 63;
    const int wave = tid >> 6;
    const int quad = lane >> 4;
    const int lrow = lane & 15;
    const int wm = (wave & 1) * 64;
    const int wn = (wave >> 1) * 64;

    // L2 panel swizzle: panel = 32 m-tiles; within panel m fastest, n slow.
    const int bid = blockIdx.x;
    const int panel = bid / 320;
    const int r = bid % 320;
    const int n0 = (r >> 5) * 128;
    const int m0 = (panel * 32 + (r & 31)) * 128;

    f32x4 acc[4][4] = {};

    for (int k0 = 0; k0 < K; k0 += 32) {
        __syncthreads();
        stage_tile(Ahi,  sAhi, tid, K, m0, k0);
        stage_tile(BhiT, sBhi, tid, K, n0, k0);
        if constexpr (SPLIT) {
            stage_tile(Alo,  sAlo, tid, K, m0, k0);
            stage_tile(BloT, sBlo, tid, K, n0, k0);
        }
        __syncthreads();

        bf16x8 ah[4], bh[4];
        #pragma unroll
        for (int i = 0; i < 4; ++i) {
            const int ao = swz_off(wm + i * 16 + lrow, quad);
            const int bo = swz_off(wn + i * 16 + lrow, quad);
            ah[i] = *(const bf16x8*)((const char*)sAhi + ao);
            bh[i] = *(const bf16x8*)((const char*)sBhi + bo);
        }
        if constexpr (SPLIT) {
            bf16x8 al[4], bl[4];
            #pragma unroll
            for (int i = 0; i < 4; ++i) {
                const int ao = swz_off(wm + i * 16 + lrow, quad);
                const int bo = swz_off(wn + i * 16 + lrow, quad);
                al[i] = *(const bf16x8*)((const char*)sAlo + ao);
                bl[i] = *(const bf16x8*)((const char*)sBlo + bo);
            }
            #pragma unroll
            for (int mt = 0; mt < 4; ++mt)
                #pragma unroll
                for (int nt = 0; nt < 4; ++nt) {
                    acc[mt][nt] = MFMA16(ah[mt], bh[nt], acc[mt][nt], 0, 0, 0);
                    acc[mt][nt] = MFMA16(ah[mt], bl[nt], acc[mt][nt], 0, 0, 0);
                    acc[mt][nt] = MFMA16(al[mt], bh[nt], acc[mt][nt], 0, 0, 0);
                }
        } else {
            #pragma unroll
            for (int mt = 0; mt < 4; ++mt)
                #pragma unroll
                for (int nt = 0; nt < 4; ++nt)
                    acc[mt][nt] = MFMA16(ah[mt], bh[nt], acc[mt][nt], 0, 0, 0);
        }
    }

    // Epilogue: C/D layout col = lane&15, row = quad*4 + reg (m89/m91-verified)
    #pragma unroll
    for (int mt = 0; mt < 4; ++mt) {
        #pragma unroll
        for (int nt = 0; nt < 4; ++nt) {
            const int col = n0 + wn + nt * 16 + lrow;
            #pragma unroll
            for (int r2 = 0; r2 < 4; ++r2) {
                const int row = m0 + wm + mt * 16 + quad * 4 + r2;
                float v = acc[mt][nt][r2];
                if constexpr (FUSE_OUT)
                    v += bias[col] + resid[(size_t)row * 1280 + col];
                Cout[(size_t)row * 1280 + col] = v;
            }
        }
    }
}

// ---------------------------------------------------------------------------
// fp32 GEMM, 64x64 tile, BK=16, 256 threads, 4x4 micro-tile. For K/V
// projections (M=616, K=2048, N=1280) — stays fp32 (feeds scoring path).
// ---------------------------------------------------------------------------
__global__ __launch_bounds__(256)
void gemm64_kernel(const float* __restrict__ A,
                   const float* __restrict__ B0, const float* __restrict__ B1,
                   float* __restrict__ C0, float* __restrict__ C1,
                   int M, int N, int K)
{
    const float* Bm = blockIdx.z ? B1 : B0;
    float* Cout = blockIdx.z ? C1 : C0;
    __shared__ float As[16][64];
    __shared__ float Bs[16][64];
    const int tid = threadIdx.x;
    const int n0 = blockIdx.x * 64;
    const int m0 = blockIdx.y * 64;
    const int tx = tid & 15, ty = tid >> 4;
    const int ar = tid >> 2;
    const int ak = (tid & 3) << 2;
    const int bk = tid >> 4;
    const int bn = (tid & 15) << 2;

    float acc[4][4] = {};
    const int arow = m0 + ar;
    const bool avalid = arow < M;
    const float* Ap = A + (size_t)arow * K + ak;
    const float* Bp = Bm + (size_t)bk * N + n0 + bn;

    for (int k0 = 0; k0 < K; k0 += 16) {
        const float4 a = avalid ? *(const float4*)(Ap + k0) : make_float4(0.f,0.f,0.f,0.f);
        const float4 b = *(const float4*)(Bp + (size_t)k0 * N);
        __syncthreads();
        As[ak+0][ar] = a.x; As[ak+1][ar] = a.y; As[ak+2][ar] = a.z; As[ak+3][ar] = a.w;
        *(float4*)&Bs[bk][bn] = b;
        __syncthreads();
        #pragma unroll
        for (int kk = 0; kk < 16; ++kk) {
            const float4 av = *(const float4*)&As[kk][ty*4];
            const float4 bv = *(const float4*)&Bs[kk][tx*4];
            const float arr[4] = {av.x, av.y, av.z, av.w};
            const float brr[4] = {bv.x, bv.y, bv.z, bv.w};
            #pragma unroll
            for (int r = 0; r < 4; ++r)
                #pragma unroll
                for (int c = 0; c < 4; ++c)
                    acc[r][c] = fmaf(arr[r], brr[c], acc[r][c]);
        }
    }
    #pragma unroll
    for (int r = 0; r < 4; ++r) {
        const int row = m0 + ty * 4 + r;
        if (row < M) {
            const float4 cv = make_float4(acc[r][0], acc[r][1], acc[r][2], acc[r][3]);
            *(float4*)(Cout + (size_t)row * N + n0 + tx * 4) = cv;
        }
    }
}

__device__ inline bool first_pair(float va, int ia, float vb, int ib)
{
    return (va > vb) || (va == vb && ia < ib);
}

// descending by (value, then index asc) — matches lax.top_k tie-break
__device__ inline void bitonic_desc(float* vals, int* idxs, int n, int tid, int nt)
{
    for (int k = 2; k <= n; k <<= 1) {
        for (int j = k >> 1; j > 0; j >>= 1) {
            __syncthreads();
            for (int i = tid; i < n; i += nt) {
                const int l = i ^ j;
                if (l > i) {
                    const float vi = vals[i], vl = vals[l];
                    const int   ii = idxs[i], il = idxs[l];
                    const bool up = (i & k) == 0;
                    const bool sw = up ? first_pair(vl, il, vi, ii)
                                       : first_pair(vi, ii, vl, il);
                    if (sw) { vals[i] = vl; vals[l] = vi; idxs[i] = il; idxs[l] = ii; }
                }
            }
        }
    }
    __syncthreads();
}

// ---------------------------------------------------------------------------
// Pass A (MFMA): swapped QK^T -> per-lane logits for 16 s-cols (s = lane&15),
// t = nt*16 + quad*4 + r. 4-product split bf16 QK (fp32-level accuracy; the
// logits feed the top-k masks, which must not flip). Softmax over t = register
// max/sum + shfl_xor(16/32) quad reduce. Accumulate sum_s p per t -> tokp.
// Grid: 2560 blocks = b(8) x h(20) x s-chunk(16); 4 waves x 4 s-tiles = 256 s.
// ---------------------------------------------------------------------------
__global__ __launch_bounds__(256)
void pass_a_kernel(const float* __restrict__ q, const float* __restrict__ kbuf,
                   float* __restrict__ tokp)
{
    __shared__ unsigned short khi[80 * 64];   // [t][d] bf16, XOR-swizzled rows
    __shared__ unsigned short klo[80 * 64];
    __shared__ float wsum[4][80];
    const int g = blockIdx.x;
    const int b = g / 320;
    const int rem = g % 320;
    const int h = rem >> 4;
    const int chunk = rem & 15;
    const int tid = threadIdx.x;

    // stage K slice -> swizzled bf16 hi/lo (T2 swizzle: byte ^= (t&7)<<4)
    for (int i = tid; i < 80 * 16; i += 256) {
        const int t = i >> 4, j = i & 15;                 // d0 = 4*j
        float4 v = make_float4(0.f, 0.f, 0.f, 0.f);
        if (t < T_) v = *(const float4*)(kbuf + (size_t)(b * T_ + t) * HD_ + h * D_ + 4 * j);
        ushort4 hh, ll;
        hh.x = f2bf(v.x); ll.x = f2bf(v.x - bf2f(hh.x));
        hh.y = f2bf(v.y); ll.y = f2bf(v.y - bf2f(hh.y));
        hh.z = f2bf(v.z); ll.z = f2bf(v.z - bf2f(hh.z));
        hh.w = f2bf(v.w); ll.w = f2bf(v.w - bf2f(hh.w));
        const int byt = t * 128 + ((8 * j) ^ ((t & 7) << 4));
        *(ushort4*)((char*)khi + byt) = hh;
        *(ushort4*)((char*)klo + byt) = ll;
    }
    __syncthreads();

    const int wid = tid >> 6, lane = tid & 63;
    const int lrow = lane & 15, quad = lane >> 4;

    f32x4 tokacc[5] = {};
    for (int st = 0; st < 4; ++st) {
        const int s = chunk * 256 + wid * 64 + st * 16 + lrow;
        const float* qp = q + (size_t)(b * S_ + s) * HD_ + h * D_;
        bf16x8 qhi[2], qlo[2];
        #pragma unroll
        for (int ks = 0; ks < 2; ++ks)
            split_frag(qp + ks * 32 + quad * 8, qhi[ks], qlo[ks]);

        f32x4 acc[5] = {};
        #pragma unroll
        for (int nt = 0; nt < 5; ++nt) {
            #pragma unroll
            for (int ks = 0; ks < 2; ++ks) {
                const int krow = nt * 16 + lrow;
                const int byt = krow * 128 + ((64 * ks + 16 * quad) ^ ((krow & 7) << 4));
                const bf16x8 kh = *(const bf16x8*)((const char*)khi + byt);
                const bf16x8 kl = *(const bf16x8*)((const char*)klo + byt);
                acc[nt] = MFMA16(kh, qhi[ks], acc[nt], 0, 0, 0);
                acc[nt] = MFMA16(kh, qlo[ks], acc[nt], 0, 0, 0);
                acc[nt] = MFMA16(kl, qhi[ks], acc[nt], 0, 0, 0);
                acc[nt] = MFMA16(kl, qlo[ks], acc[nt], 0, 0, 0);
            }
        }
        float m = -1e30f;
        #pragma unroll
        for (int nt = 0; nt < 5; ++nt)
            #pragma unroll
            for (int r = 0; r < 4; ++r) {
                const int t = nt * 16 + quad * 4 + r;
                const float l = (t < T_) ? acc[nt][r] * SCALE_ : -1e30f;
                acc[nt][r] = l;
                m = fmaxf(m, l);
            }
        m = fmaxf(m, __shfl_xor(m, 16, 64));
        m = fmaxf(m, __shfl_xor(m, 32, 64));
        float Lp = 0.f;
        #pragma unroll
        for (int nt = 0; nt < 5; ++nt)
            #pragma unroll
            for (int r = 0; r < 4; ++r) {
                const float e = __expf(acc[nt][r] - m);
                acc[nt][r] = e;
                Lp += e;
            }
        float L = Lp + __shfl_xor(Lp, 16, 64);
        L += __shfl_xor(L, 32, 64);
        const float invL = 1.0f / L;
        #pragma unroll
        for (int nt = 0; nt < 5; ++nt)
            #pragma unroll
            for (int r = 0; r < 4; ++r)
                tokacc[nt][r] = fmaf(acc[nt][r], invL, tokacc[nt][r]);
    }
    // reduce over the 16 s-columns (lane bits 0..3), write per-wave partials
    #pragma unroll
    for (int nt = 0; nt < 5; ++nt)
        #pragma unroll
        for (int r = 0; r < 4; ++r) {
            float v = tokacc[nt][r];
            v += __shfl_xor(v, 1, 64);
            v += __shfl_xor(v, 2, 64);
            v += __shfl_xor(v, 4, 64);
            v += __shfl_xor(v, 8, 64);
            if (lrow == 0) wsum[wid][nt * 16 + quad * 4 + r] = v;
        }
    __syncthreads();
    for (int t = tid; t < T_; t += 256)
        tokp[(size_t)g * T_ + t] = (wsum[0][t] + wsum[1][t]) + (wsum[2][t] + wsum[3][t]);
}

// ---------------------------------------------------------------------------
// Top-k over 77 token scores per batch -> tok_mask. 8 blocks x 128 threads.
// ---------------------------------------------------------------------------
__global__ __launch_bounds__(128)
void topk_tok_kernel(const float* __restrict__ tokp, float* __restrict__ tokm)
{
    __shared__ float vals[128];
    __shared__ int idxs[128];
    const int b = blockIdx.x, tid = threadIdx.x;
    float v = -1e30f;
    if (tid < T_) {
        float sm = 0.f;
        for (int j = 0; j < 320; ++j) sm += tokp[(size_t)(b * 320 + j) * T_ + tid];
        v = sm;
    }
    vals[tid] = v; idxs[tid] = tid;
    bitonic_desc(vals, idxs, 128, tid, 128);
    if (tid < T_) tokm[b * T_ + tid] = 0.f;
    __syncthreads();
    if (tid < KTOK_) tokm[b * T_ + idxs[tid]] = 1.0f;
}

// ---------------------------------------------------------------------------
// K/V cross-frame mixing: kd = k2-k (delta, mask folded in), v2 = mixed v.
// ---------------------------------------------------------------------------
__global__ __launch_bounds__(256)
void mix_kernel(const float* __restrict__ kbuf, const float* __restrict__ vbuf,
                const float* __restrict__ tokm,
                float* __restrict__ kd, float* __restrict__ v2)
{
    const int i = blockIdx.x * 256 + threadIdx.x;   // < 77*1280 = 98560
    const int t = i / HD_;
    float ks = 0.f, vs = 0.f;
    #pragma unroll
    for (int b = 0; b < B_; ++b) {
        ks += kbuf[(size_t)b * T_ * HD_ + i];
        vs += vbuf[(size_t)b * T_ * HD_ + i];
    }
    #pragma unroll
    for (int b = 0; b < B_; ++b) {
        const size_t gi = (size_t)b * T_ * HD_ + i;
        const float msk = tokm[b * T_ + t];
        const float kx = kbuf[gi], vx = vbuf[gi];
        kd[gi] = CMIX_ * msk * ((ks - 8.f * kx) * (1.0f / 7.0f));
        v2[gi] = vx + CMIX_ * msk * ((vs - 8.f * vx) * (1.0f / 7.0f));
    }
}

// ---------------------------------------------------------------------------
// Fused pass B+C (MFMA): swapped QK^T gives per-lane l1 (split, 4 products)
// and l2 = l1 + q·kd (kd bf16-hi; mask folded into kd). Register softmax for
// both; posp = masked mass of softmax(l1); p2 = softmax(l2) -> LDS round-trip
// per 32-wide k-step (hi/lo) -> swapped PV mfma(V^T, P) -> ctx.
// ---------------------------------------------------------------------------
__global__ __launch_bounds__(256)
void pass_bc_kernel(const float* __restrict__ q, const float* __restrict__ kbuf,
                    const float* __restrict__ kd, const float* __restrict__ v2,
                    const float* __restrict__ tokm,
                    float* __restrict__ posp, float* __restrict__ ctx)
{
    __shared__ unsigned short khi[80 * 64];     // [t][d] XOR-swizzled
    __shared__ unsigned short klo[80 * 64];
    __shared__ unsigned short kdh[80 * 64];
    __shared__ unsigned short vThi[64 * 88];    // [d][t] rows padded to 88
    __shared__ unsigned short vTlo[64 * 88];
    __shared__ unsigned short vguard[128];      // zeroed guard for vT overreads
    __shared__ unsigned short Pbuf[4][2][16 * 40]; // per-wave [hi/lo][s][tloc]
    __shared__ float smaskf[80];

    const int g = blockIdx.x;
    const int b = g / 320;
    const int rem = g % 320;
    const int h = rem >> 4;
    const int chunk = rem & 15;
    const int tid = threadIdx.x;

    // ---- stage K (hi/lo) + Kd (hi), swizzled ----
    for (int i = tid; i < 80 * 16; i += 256) {
        const int t = i >> 4, j = i & 15;
        float4 vk = make_float4(0.f, 0.f, 0.f, 0.f);
        float4 vd = make_float4(0.f, 0.f, 0.f, 0.f);
        if (t < T_) {
            const size_t gi = (size_t)(b * T_ + t) * HD_ + h * D_ + 4 * j;
            vk = *(const float4*)(kbuf + gi);
            vd = *(const float4*)(kd + gi);
        }
        ushort4 hh, ll, dd;
        hh.x = f2bf(vk.x); ll.x = f2bf(vk.x - bf2f(hh.x)); dd.x = f2bf(vd.x);
        hh.y = f2bf(vk.y); ll.y = f2bf(vk.y - bf2f(hh.y)); dd.y = f2bf(vd.y);
        hh.z = f2bf(vk.z); ll.z = f2bf(vk.z - bf2f(hh.z)); dd.z = f2bf(vd.z);
        hh.w = f2bf(vk.w); ll.w = f2bf(vk.w - bf2f(hh.w)); dd.w = f2bf(vd.w);
        const int byt = t * 128 + ((8 * j) ^ ((t & 7) << 4));
        *(ushort4*)((char*)khi + byt) = hh;
        *(ushort4*)((char*)klo + byt) = ll;
        *(ushort4*)((char*)kdh + byt) = dd;
    }
    // ---- stage V^T (hi/lo): rows d (88 cols, zero-padded past t=76) ----
    for (int i = tid; i < 64 * 22; i += 256) {
        const int d = i / 22, jg = i - d * 22;           // cols t = 4*jg..+3
        float vv[4];
        #pragma unroll
        for (int r = 0; r < 4; ++r) {
            const int t = 4 * jg + r;
            vv[r] = (t < T_) ? v2[(size_t)(b * T_ + t) * HD_ + h * D_ + d] : 0.f;
        }
        ushort4 hh, ll;
        hh.x = f2bf(vv[0]); ll.x = f2bf(vv[0] - bf2f(hh.x));
        hh.y = f2bf(vv[1]); ll.y = f2bf(vv[1] - bf2f(hh.y));
        hh.z = f2bf(vv[2]); ll.z = f2bf(vv[2] - bf2f(hh.z));
        hh.w = f2bf(vv[3]); ll.w = f2bf(vv[3] - bf2f(hh.w));
        const int byt = d * 176 + 8 * jg;
        *(ushort4*)((char*)vThi + byt) = hh;
        *(ushort4*)((char*)vTlo + byt) = ll;
    }
    for (int t = tid; t < 80; t += 256) smaskf[t] = (t < T_) ? tokm[b * T_ + t] : 0.f;
    for (int i = tid; i < 128; i += 256) vguard[i] = 0;
    __syncthreads();

    const int wid = tid >> 6, lane = tid & 63;
    const int lrow = lane & 15, quad = lane >> 4;
    unsigned short* Ph = &Pbuf[wid][0][0];
    unsigned short* Pl = &Pbuf[wid][1][0];

    // hoist per-lane token-mask values (constant across s-tiles)
    float smv[5][4];
    #pragma unroll
    for (int nt = 0; nt < 5; ++nt)
        #pragma unroll
        for (int r = 0; r < 4; ++r)
            smv[nt][r] = smaskf[nt * 16 + quad * 4 + r];

    for (int st = 0; st < 4; ++st) {
        const int s = chunk * 256 + wid * 64 + st * 16 + lrow;
        const float* qp = q + (size_t)(b * S_ + s) * HD_ + h * D_;
        bf16x8 qhi[2], qlo[2];
        #pragma unroll
        for (int ks = 0; ks < 2; ++ks)
            split_frag(qp + ks * 32 + quad * 8, qhi[ks], qlo[ks]);

        f32x4 acc1[5] = {}, accd[5] = {};
        #pragma unroll
        for (int nt = 0; nt < 5; ++nt) {
            #pragma unroll
            for (int ks = 0; ks < 2; ++ks) {
                const int krow = nt * 16 + lrow;
                const int byt = krow * 128 + ((64 * ks + 16 * quad) ^ ((krow & 7) << 4));
                const bf16x8 kh = *(const bf16x8*)((const char*)khi + byt);
                const bf16x8 kl = *(const bf16x8*)((const char*)klo + byt);
                const bf16x8 kdv = *(const bf16x8*)((const char*)kdh + byt);
                acc1[nt] = MFMA16(kh, qhi[ks], acc1[nt], 0, 0, 0);
                acc1[nt] = MFMA16(kh, qlo[ks], acc1[nt], 0, 0, 0);
                acc1[nt] = MFMA16(kl, qhi[ks], acc1[nt], 0, 0, 0);
                acc1[nt] = MFMA16(kl, qlo[ks], acc1[nt], 0, 0, 0);
                accd[nt] = MFMA16(kdv, qhi[ks], accd[nt], 0, 0, 0);
            }
        }

        // logits + dual softmax (l1: pos score; l2: second attention)
        float m1 = -1e30f, m2 = -1e30f;
        f32x4 l2v[5];
        #pragma unroll
        for (int nt = 0; nt < 5; ++nt)
            #pragma unroll
            for (int r = 0; r < 4; ++r) {
                const int t = nt * 16 + quad * 4 + r;
                const bool valid = t < T_;
                const float l1 = valid ? acc1[nt][r] * SCALE_ : -1e30f;
                const float l2 = valid ? l1 + accd[nt][r] * SCALE_ : -1e30f;
                acc1[nt][r] = l1;
                l2v[nt][r] = l2;
                m1 = fmaxf(m1, l1);
                m2 = fmaxf(m2, l2);
            }
        m1 = fmaxf(m1, __shfl_xor(m1, 16, 64));
        m1 = fmaxf(m1, __shfl_xor(m1, 32, 64));
        m2 = fmaxf(m2, __shfl_xor(m2, 16, 64));
        m2 = fmaxf(m2, __shfl_xor(m2, 32, 64));
        float L1p = 0.f, Smp = 0.f, L2p = 0.f;
        #pragma unroll
        for (int nt = 0; nt < 5; ++nt)
            #pragma unroll
            for (int r = 0; r < 4; ++r) {
                const float e1 = __expf(acc1[nt][r] - m1);
                L1p += e1;
                Smp = fmaf(e1, smv[nt][r], Smp);
                const float e2 = __expf(l2v[nt][r] - m2);
                l2v[nt][r] = e2;
                L2p += e2;
            }
        float L1 = L1p + __shfl_xor(L1p, 16, 64); L1 += __shfl_xor(L1, 32, 64);
        float Sm = Smp + __shfl_xor(Smp, 16, 64); Sm += __shfl_xor(Sm, 32, 64);
        float L2 = L2p + __shfl_xor(L2p, 16, 64); L2 += __shfl_xor(L2, 32, 64);
        if (quad == 0) posp[(size_t)(b * H_ + h) * S_ + s] = Sm / L1;
        const float invL2 = 1.0f / L2;
        #pragma unroll
        for (int nt = 0; nt < 5; ++nt)
            #pragma unroll
            for (int r = 0; r < 4; ++r)
                l2v[nt][r] *= invL2;

        // PV: per 32-wide k-step, P -> LDS (hi/lo) -> B-frags, V^T A-frags
        f32x4 pv[4] = {};
        #pragma unroll
        for (int ks = 0; ks < 3; ++ks) {
            asm volatile("s_waitcnt lgkmcnt(0)" ::: "memory");
            __builtin_amdgcn_sched_barrier(0);
            #pragma unroll
            for (int half = 0; half < 2; ++half) {
                const int nt = 2 * ks + half;
                ushort4 ph = {0, 0, 0, 0}, plw = {0, 0, 0, 0};
                if (nt < 5) {
                    ph.x = f2bf(l2v[nt][0]); plw.x = f2bf(l2v[nt][0] - bf2f(ph.x));
                    ph.y = f2bf(l2v[nt][1]); plw.y = f2bf(l2v[nt][1] - bf2f(ph.y));
                    ph.z = f2bf(l2v[nt][2]); plw.z = f2bf(l2v[nt][2] - bf2f(ph.z));
                    ph.w = f2bf(l2v[nt][3]); plw.w = f2bf(l2v[nt][3] - bf2f(ph.w));
                }
                const int pb = lrow * 80 + 32 * half + 8 * quad;
                *(ushort4*)((char*)Ph + pb) = ph;
                *(ushort4*)((char*)Pl + pb) = plw;
            }
            asm volatile("s_waitcnt lgkmcnt(0)" ::: "memory");
            __builtin_amdgcn_sched_barrier(0);
            const bf16x8 pH = *(const bf16x8*)((const char*)Ph + lrow * 80 + quad * 16);
            const bf16x8 pL = *(const bf16x8*)((const char*)Pl + lrow * 80 + quad * 16);
            #pragma unroll
            for (int mt = 0; mt < 4; ++mt) {
                const int vb = (mt * 16 + lrow) * 176 + 64 * ks + 16 * quad;
                const bf16x8 vH = *(const bf16x8*)((const char*)vThi + vb);
                const bf16x8 vL = *(const bf16x8*)((const char*)vTlo + vb);
                pv[mt] = MFMA16(vH, pH, pv[mt], 0, 0, 0);
                pv[mt] = MFMA16(vH, pL, pv[mt], 0, 0, 0);
                pv[mt] = MFMA16(vL, pH, pv[mt], 0, 0, 0);
            }
        }
        // ctx write: col = lane&15 = s, row(d) = mt*16 + quad*4 + reg
        float* cp = ctx + (size_t)(b * S_ + s) * HD_ + h * D_;
        #pragma unroll
        for (int mt = 0; mt < 4; ++mt) {
            const float4 o = make_float4(pv[mt][0], pv[mt][1], pv[mt][2], pv[mt][3]);
            *(float4*)(cp + mt * 16 + quad * 4) = o;
        }
    }
}

// ---------------------------------------------------------------------------
// Top-k over 4096 position scores per batch -> pos_mask. 8 blocks x 1024.
// ---------------------------------------------------------------------------
__global__ __launch_bounds__(1024)
void topk_pos_kernel(const float* __restrict__ posp, float* __restrict__ posm)
{
    __shared__ float vals[S_];
    __shared__ int idxs[S_];
    const int b = blockIdx.x, tid = threadIdx.x;
    for (int s = tid; s < S_; s += 1024) {
        float sm = 0.f;
        for (int h = 0; h < H_; ++h) sm += posp[(size_t)(b * H_ + h) * S_ + s];
        vals[s] = sm; idxs[s] = s;
    }
    bitonic_desc(vals, idxs, S_, tid, 1024);
    for (int s = tid; s < S_; s += 1024) posm[b * S_ + s] = 0.f;
    __syncthreads();
    for (int i = tid; i < KPOS_; i += 1024) posm[b * S_ + idxs[i]] = 1.0f;
}

// ---------------------------------------------------------------------------
// Batch-sum of context over b: csum[s,hd] = sum_b ctx[b,s,hd]. float4 lanes.
// ---------------------------------------------------------------------------
__global__ __launch_bounds__(256)
void ctxsum_kernel(const float* __restrict__ ctx, float* __restrict__ csum)
{
    const size_t i = (size_t)blockIdx.x * 256 + threadIdx.x;  // float4 index
    const float4* c = (const float4*)ctx;
    float4 a = c[i];
    #pragma unroll
    for (int b = 1; b < B_; ++b) {
        const float4 x = c[(size_t)b * (S_ * HD_ / 4) + i];
        a.x += x.x; a.y += x.y; a.z += x.z; a.w += x.w;
    }
    ((float4*)csum)[i] = a;
}

// ---------------------------------------------------------------------------
extern "C" void kernel_launch(void* const* d_in, const int* in_sizes, int n_in,
                              void* d_out, int out_size, void* d_ws, size_t ws_size,
                              hipStream_t stream)
{
    const float* hidden = (const float*)d_in[0];
    const float* enc    = (const float*)d_in[1];
    const float* Wq     = (const float*)d_in[2];
    const float* Wk     = (const float*)d_in[3];
    const float* Wv     = (const float*)d_in[4];
    const float* Wo     = (const float*)d_in[5];
    const float* bo     = (const float*)d_in[6];
    float* out = (float*)d_out;

    char* w = (char*)d_ws;
    float* q    = (float*)w; w += (size_t)M1_ * HD_ * 4;
    float* ctx  = (float*)w; w += (size_t)M1_ * HD_ * 4;
    float* kbuf = (float*)w; w += (size_t)B_ * T_ * HD_ * 4;
    float* vbuf = (float*)w; w += (size_t)B_ * T_ * HD_ * 4;
    float* kd   = (float*)w; w += (size_t)B_ * T_ * HD_ * 4;
    float* v2   = (float*)w; w += (size_t)B_ * T_ * HD_ * 4;
    float* csum = (float*)w; w += (size_t)S_ * HD_ * 4;
    float* tokp = (float*)w; w += (size_t)2560 * T_ * 4;
    float* posp = (float*)w; w += (size_t)B_ * H_ * S_ * 4;
    float* tokm = (float*)w; w += (size_t)B_ * T_ * 4;
    float* posm = (float*)w; w += (size_t)B_ * S_ * 4;
    unsigned short* Ahi   = (unsigned short*)w; w += (size_t)M1_ * HD_ * 2;
    unsigned short* Alo   = (unsigned short*)w; w += (size_t)M1_ * HD_ * 2;
    unsigned short* ctxb  = (unsigned short*)w; w += (size_t)M1_ * HD_ * 2;
    unsigned short* WqhiT = (unsigned short*)w; w += (size_t)C_ * HD_ * 2;
    unsigned short* WqloT = (unsigned short*)w; w += (size_t)C_ * HD_ * 2;
    unsigned short* WohiT = (unsigned short*)w; w += (size_t)HD_ * C_ * 2;
    unsigned short* WoloT = (unsigned short*)w; w += (size_t)HD_ * C_ * 2;
    (void)ws_size; (void)in_sizes; (void)n_in; (void)out_size;

    // 1. Split hidden -> bf16 hi/lo; weights -> transposed bf16 hi/lo
    split_convert_kernel<<<M1_ * HD_ / 4 / 256, 256, 0, stream>>>(hidden, Ahi, Alo);
    wsplitT_kernel<<<dim3(40, 40), 256, 0, stream>>>(Wq, WqhiT, WqloT);
    wsplitT_kernel<<<dim3(40, 40), 256, 0, stream>>>(Wo, WohiT, WoloT);
    // 2. Q projection: split-bf16 MFMA (3 products ~ fp32 accuracy)
    mfma_gemm_kernel<true, false><<<2560, 256, 0, stream>>>(
        Ahi, Alo, WqhiT, WqloT, q, C_, nullptr, nullptr);
    // 3. K and V projections (fp32 — feeds scoring path)
    gemm64_kernel<<<dim3(20, 10, 2), 256, 0, stream>>>(
        enc, Wk, Wv, kbuf, vbuf, MKV_, HD_, CENC_);
    // 4. First attention (MFMA) -> token-score partials
    pass_a_kernel<<<2560, 256, 0, stream>>>(q, kbuf, tokp);
    // 5. Token top-k mask
    topk_tok_kernel<<<8, 128, 0, stream>>>(tokp, tokm);
    // 6. Cross-frame K/V mixing
    mix_kernel<<<385, 256, 0, stream>>>(kbuf, vbuf, tokm, kd, v2);
    // 7. Fused pass B (pos scores) + pass C (second attention, MFMA)
    pass_bc_kernel<<<2560, 256, 0, stream>>>(q, kbuf, kd, v2, tokm, posp, ctx);
    // 8. Position top-k mask
    topk_pos_kernel<<<8, 1024, 0, stream>>>(posp, posm);
    // 9. Batch-sum of context for mean-of-others injection
    ctxsum_kernel<<<S_ * HD_ / 4 / 256, 256, 0, stream>>>(ctx, csum);
    // 10. Injection + bf16 convert of context (A operand of O-proj)
    inject_convert_kernel<<<M1_ * HD_ / 4 / 256, 256, 0, stream>>>(ctx, csum, posm, ctxb);
    // 11. O projection: plain bf16 MFMA + bias + residual epilogue
    mfma_gemm_kernel<false, true><<<2560, 256, 0, stream>>>(
        ctxb, nullptr, WohiT, nullptr, out, HD_, bo, hidden);
}

// Round 3
// 1535.198 us; speedup vs baseline: 1.4290x; 1.0067x over previous
//
#include <hip/hip_runtime.h>
#include <math.h>

// Problem constants
#define B_    8
#define S_    4096
#define T_    77
#define C_    1280
#define CENC_ 2048
#define H_    20
#define D_    64
#define HD_   1280
#define M1_   (B_*S_)     // 32768 rows for Q / O GEMMs
#define MKV_  (B_*T_)     // 616 rows for K/V GEMM
#define KTOK_ 12          // ceil(77*0.15)
#define KPOS_ 1229        // ceil(4096*0.3)
#define SCALE_ 0.125f     // 1/sqrt(64)
#define CMIX_  0.15f      // STRENGTH*(1-ALPHA)
#define CINJ_  (0.25f/7.0f) // FIW*STRENGTH/(B-1)

typedef __attribute__((ext_vector_type(8))) short bf16x8;
typedef __attribute__((ext_vector_type(4))) float f32x4;

#define AS_G __attribute__((address_space(1)))
#define AS_L __attribute__((address_space(3)))
#define MFMA16 __builtin_amdgcn_mfma_f32_16x16x32_bf16
#define SBAR() asm volatile("s_barrier" ::: "memory")

// ---------------------------------------------------------------------------
// bf16 helpers (RNE)
// ---------------------------------------------------------------------------
__device__ inline unsigned short f2bf(float x)
{
    union { float f; unsigned u; } v; v.f = x;
    const unsigned r = v.u + 0x7FFFu + ((v.u >> 16) & 1u);
    return (unsigned short)(r >> 16);
}
__device__ inline float bf2f(unsigned short h)
{
    union { float f; unsigned u; } v; v.u = ((unsigned)h) << 16;
    return v.f;
}

// split 8 consecutive fp32 -> bf16 hi + lo fragments (two aligned float4s)
__device__ inline void split_frag(const float* __restrict__ p, bf16x8& hi, bf16x8& lo)
{
    const float4 a = *(const float4*)p;
    const float4 b = *(const float4*)(p + 4);
    float f[8] = {a.x, a.y, a.z, a.w, b.x, b.y, b.z, b.w};
    #pragma unroll
    for (int e = 0; e < 8; ++e) {
        const unsigned short h = f2bf(f[e]);
        hi[e] = (short)h;
        lo[e] = (short)f2bf(f[e] - bf2f(h));
    }
}

// ---------------------------------------------------------------------------
// Split fp32 -> bf16 hi + bf16 lo (residual). One float4 per thread.
// ---------------------------------------------------------------------------
__global__ __launch_bounds__(256)
void split_convert_kernel(const float* __restrict__ x, unsigned short* __restrict__ hi,
                          unsigned short* __restrict__ lo)
{
    const size_t i4 = (size_t)blockIdx.x * 256 + threadIdx.x;
    const float4 v = ((const float4*)x)[i4];
    ushort4 h, l;
    h.x = f2bf(v.x); l.x = f2bf(v.x - bf2f(h.x));
    h.y = f2bf(v.y); l.y = f2bf(v.y - bf2f(h.y));
    h.z = f2bf(v.z); l.z = f2bf(v.z - bf2f(h.z));
    h.w = f2bf(v.w); l.w = f2bf(v.w - bf2f(h.w));
    ((ushort4*)hi)[i4] = h;
    ((ushort4*)lo)[i4] = l;
}

// ---------------------------------------------------------------------------
// Weight transpose + split: W[K=1280][N=1280] fp32 -> Thi/Tlo [N][K] bf16.
// ---------------------------------------------------------------------------
__global__ __launch_bounds__(256)
void wsplitT_kernel(const float* __restrict__ W, unsigned short* __restrict__ Thi,
                    unsigned short* __restrict__ Tlo)
{
    __shared__ float tile[32][33];
    const int tx = threadIdx.x & 31, ty = threadIdx.x >> 5;
    const int n0 = blockIdx.x * 32, k0 = blockIdx.y * 32;
    #pragma unroll
    for (int i = 0; i < 4; ++i) {
        const int kk = ty + i * 8;
        tile[kk][tx] = W[(size_t)(k0 + kk) * 1280 + n0 + tx];
    }
    __syncthreads();
    #pragma unroll
    for (int i = 0; i < 4; ++i) {
        const int nn = ty + i * 8;
        const float v = tile[tx][nn];               // = W[k0+tx][n0+nn]
        const unsigned short h = f2bf(v);
        const size_t oi = (size_t)(n0 + nn) * 1280 + k0 + tx;
        Thi[oi] = h;
        Tlo[oi] = f2bf(v - bf2f(h));
    }
}

// ---------------------------------------------------------------------------
// Injection + fp32->bf16 for the O-projection A operand:
// a = ctx*(1-8*cf) + cf*csum, cf = posm[row]*CINJ_.
// ---------------------------------------------------------------------------
__global__ __launch_bounds__(256)
void inject_convert_kernel(const float* __restrict__ ctx, const float* __restrict__ csum,
                           const float* __restrict__ posm, unsigned short* __restrict__ outb)
{
    const size_t i4 = (size_t)blockIdx.x * 256 + threadIdx.x;   // float4 index
    const int row = (int)(i4 / 320);
    const int c4  = (int)(i4 % 320);
    const float cf = posm[row] * CINJ_;
    const float am = 1.0f - 8.0f * cf;
    const float4 c  = ((const float4*)ctx)[i4];
    const float4 cs = ((const float4*)csum)[(size_t)(row & (S_ - 1)) * 320 + c4];
    ushort4 h;
    h.x = f2bf(c.x * am + cf * cs.x);
    h.y = f2bf(c.y * am + cf * cs.y);
    h.z = f2bf(c.z * am + cf * cs.z);
    h.w = f2bf(c.w * am + cf * cs.w);
    ((ushort4*)outb)[i4] = h;
}

// ---------------------------------------------------------------------------
// MFMA GEMM: C[M x 1280] = A[M x K] * B[K x 1280], A and B^T given in bf16.
// 128x128 tile, BK=32, 4 waves (2x2 of 64x64), 16x16x32 bf16 MFMA.
// SPLIT: acc += Ah*Bh + Ah*Bl + Al*Bh (fp32-ish accuracy).
//
// r1: conflict-free pair-packed XOR LDS layout (kept; conflicts = 0).
// r2: T3+T4 pipeline — double-buffered LDS, prefetch tile k+1 issued before
// computing tile k, COUNTED s_waitcnt vmcnt(8/4) (never 0 in steady state),
// raw s_barrier (loads stay in flight across it), setprio(1) around MFMA.
// Hazards: barrier-A after each wave's counted wait => all waves' cur-tile
// loads resident before ds_read; barrier-B after MFMA => all reads of
// buf[cur] done before iter k+1's STAGE overwrites it.
// ---------------------------------------------------------------------------
__device__ inline void stage_tile(const unsigned short* __restrict__ gsrc,
                                  unsigned short* lds, int tid, int ldK,
                                  int row0, int k0)
{
    #pragma unroll
    for (int c0 = 0; c0 < 512; c0 += 256) {
        const int c = c0 + tid;                    // 16-B chunk index in LDS
        const int rr = c >> 3;                     // packed row (2 logical rows)
        const int l  = (c & 7) ^ (rr & 7);         // logical chunk (involution)
        const int row = 2 * rr + (l >> 2);         // logical tile row
        const int j   = l & 3;                     // 16-B k-chunk within row
        const unsigned short* gp = gsrc + (size_t)(row0 + row) * ldK + k0 + j * 8;
        __builtin_amdgcn_global_load_lds((const AS_G void*)gp, (AS_L void*)(lds + (size_t)c * 8),
                                         16, 0, 0);
    }
}

// swizzled read offset (in bytes) for logical (row, 16-B chunk quad)
__device__ inline int swz_off(int row, int quad)
{
    const int rr = row >> 1;
    const int pos = (((row & 1) << 2) | quad) ^ (rr & 7);
    return rr * 128 + pos * 16;
}

template<bool SPLIT, bool FUSE_OUT>
__global__ __launch_bounds__(256)
void mfma_gemm_kernel(const unsigned short* __restrict__ Ahi, const unsigned short* __restrict__ Alo,
                      const unsigned short* __restrict__ BhiT, const unsigned short* __restrict__ BloT,
                      float* __restrict__ Cout, int K,
                      const float* __restrict__ bias, const float* __restrict__ resid)
{
    __shared__ unsigned short sAhi[2][128 * 32];
    __shared__ unsigned short sBhi[2][128 * 32];
    __shared__ unsigned short sAlo[SPLIT ? 2 : 1][SPLIT ? 128 * 32 : 8];
    __shared__ unsigned short sBlo[SPLIT ? 2 : 1][SPLIT ? 128 * 32 : 8];

    const int tid  = threadIdx.x;
    const int lane = tid & 63;
    const int wave = tid >> 6;
    const int quad = lane >> 4;
    const int lrow = lane & 15;
    const int wm = (wave & 1) * 64;
    const int wn = (wave >> 1) * 64;

    // L2 panel swizzle: panel = 32 m-tiles; within panel m fastest, n slow.
    const int bid = blockIdx.x;
    const int panel = bid / 320;
    const int r = bid % 320;
    const int n0 = (r >> 5) * 128;
    const int m0 = (panel * 32 + (r & 31)) * 128;

    f32x4 acc[4][4] = {};

    auto stage_all = [&](int bufi, int k0) {
        stage_tile(Ahi,  sAhi[bufi], tid, K, m0, k0);
        stage_tile(BhiT, sBhi[bufi], tid, K, n0, k0);
        if constexpr (SPLIT) {
            stage_tile(Alo,  sAlo[bufi], tid, K, m0, k0);
            stage_tile(BloT, sBlo[bufi], tid, K, n0, k0);
        }
    };

    const int NK = K >> 5;            // BK=32 steps (K=1280 -> 40)
    stage_all(0, 0);                  // prologue prefetch

    for (int kt = 0; kt < NK; ++kt) {
        const int cur = kt & 1;
        if (kt + 1 < NK) {
            stage_all(cur ^ 1, (kt + 1) << 5);   // prefetch next tile
            // counted wait: only the 8 (SPLIT) / 4 loads just issued may
            // remain outstanding -> current tile's loads are complete.
            if constexpr (SPLIT)
                asm volatile("s_waitcnt vmcnt(8)" ::: "memory");
            else
                asm volatile("s_waitcnt vmcnt(4)" ::: "memory");
        } else {
            asm volatile("s_waitcnt vmcnt(0)" ::: "memory");
        }
        SBAR();   // barrier A: all waves' current-tile loads resident

        bf16x8 ah[4], bh[4];
        #pragma unroll
        for (int i = 0; i < 4; ++i) {
            const int ao = swz_off(wm + i * 16 + lrow, quad);
            const int bo = swz_off(wn + i * 16 + lrow, quad);
            ah[i] = *(const bf16x8*)((const char*)sAhi[cur] + ao);
            bh[i] = *(const bf16x8*)((const char*)sBhi[cur] + bo);
        }
        if constexpr (SPLIT) {
            bf16x8 al[4], bl[4];
            #pragma unroll
            for (int i = 0; i < 4; ++i) {
                const int ao = swz_off(wm + i * 16 + lrow, quad);
                const int bo = swz_off(wn + i * 16 + lrow, quad);
                al[i] = *(const bf16x8*)((const char*)sAlo[cur] + ao);
                bl[i] = *(const bf16x8*)((const char*)sBlo[cur] + bo);
            }
            __builtin_amdgcn_s_setprio(1);
            #pragma unroll
            for (int mt = 0; mt < 4; ++mt)
                #pragma unroll
                for (int nt = 0; nt < 4; ++nt) {
                    acc[mt][nt] = MFMA16(ah[mt], bh[nt], acc[mt][nt], 0, 0, 0);
                    acc[mt][nt] = MFMA16(ah[mt], bl[nt], acc[mt][nt], 0, 0, 0);
                    acc[mt][nt] = MFMA16(al[mt], bh[nt], acc[mt][nt], 0, 0, 0);
                }
            __builtin_amdgcn_s_setprio(0);
        } else {
            __builtin_amdgcn_s_setprio(1);
            #pragma unroll
            for (int mt = 0; mt < 4; ++mt)
                #pragma unroll
                for (int nt = 0; nt < 4; ++nt)
                    acc[mt][nt] = MFMA16(ah[mt], bh[nt], acc[mt][nt], 0, 0, 0);
            __builtin_amdgcn_s_setprio(0);
        }
        SBAR();   // barrier B: all reads of buf[cur] done before overwrite
    }

    // Epilogue: C/D layout col = lane&15, row = quad*4 + reg (m89/m91-verified)
    #pragma unroll
    for (int mt = 0; mt < 4; ++mt) {
        #pragma unroll
        for (int nt = 0; nt < 4; ++nt) {
            const int col = n0 + wn + nt * 16 + lrow;
            #pragma unroll
            for (int r2 = 0; r2 < 4; ++r2) {
                const int row = m0 + wm + mt * 16 + quad * 4 + r2;
                float v = acc[mt][nt][r2];
                if constexpr (FUSE_OUT)
                    v += bias[col] + resid[(size_t)row * 1280 + col];
                Cout[(size_t)row * 1280 + col] = v;
            }
        }
    }
}

// ---------------------------------------------------------------------------
// fp32 GEMM, 64x64 tile, BK=16, 256 threads, 4x4 micro-tile. For K/V
// projections (M=616, K=2048, N=1280) — stays fp32 (feeds scoring path).
// ---------------------------------------------------------------------------
__global__ __launch_bounds__(256)
void gemm64_kernel(const float* __restrict__ A,
                   const float* __restrict__ B0, const float* __restrict__ B1,
                   float* __restrict__ C0, float* __restrict__ C1,
                   int M, int N, int K)
{
    const float* Bm = blockIdx.z ? B1 : B0;
    float* Cout = blockIdx.z ? C1 : C0;
    __shared__ float As[16][64];
    __shared__ float Bs[16][64];
    const int tid = threadIdx.x;
    const int n0 = blockIdx.x * 64;
    const int m0 = blockIdx.y * 64;
    const int tx = tid & 15, ty = tid >> 4;
    const int ar = tid >> 2;
    const int ak = (tid & 3) << 2;
    const int bk = tid >> 4;
    const int bn = (tid & 15) << 2;

    float acc[4][4] = {};
    const int arow = m0 + ar;
    const bool avalid = arow < M;
    const float* Ap = A + (size_t)arow * K + ak;
    const float* Bp = Bm + (size_t)bk * N + n0 + bn;

    for (int k0 = 0; k0 < K; k0 += 16) {
        const float4 a = avalid ? *(const float4*)(Ap + k0) : make_float4(0.f,0.f,0.f,0.f);
        const float4 b = *(const float4*)(Bp + (size_t)k0 * N);
        __syncthreads();
        As[ak+0][ar] = a.x; As[ak+1][ar] = a.y; As[ak+2][ar] = a.z; As[ak+3][ar] = a.w;
        *(float4*)&Bs[bk][bn] = b;
        __syncthreads();
        #pragma unroll
        for (int kk = 0; kk < 16; ++kk) {
            const float4 av = *(const float4*)&As[kk][ty*4];
            const float4 bv = *(const float4*)&Bs[kk][tx*4];
            const float arr[4] = {av.x, av.y, av.z, av.w};
            const float brr[4] = {bv.x, bv.y, bv.z, bv.w};
            #pragma unroll
            for (int r = 0; r < 4; ++r)
                #pragma unroll
                for (int c = 0; c < 4; ++c)
                    acc[r][c] = fmaf(arr[r], brr[c], acc[r][c]);
        }
    }
    #pragma unroll
    for (int r = 0; r < 4; ++r) {
        const int row = m0 + ty * 4 + r;
        if (row < M) {
            const float4 cv = make_float4(acc[r][0], acc[r][1], acc[r][2], acc[r][3]);
            *(float4*)(Cout + (size_t)row * N + n0 + tx * 4) = cv;
        }
    }
}

__device__ inline bool first_pair(float va, int ia, float vb, int ib)
{
    return (va > vb) || (va == vb && ia < ib);
}

// descending by (value, then index asc) — matches lax.top_k tie-break
__device__ inline void bitonic_desc(float* vals, int* idxs, int n, int tid, int nt)
{
    for (int k = 2; k <= n; k <<= 1) {
        for (int j = k >> 1; j > 0; j >>= 1) {
            __syncthreads();
            for (int i = tid; i < n; i += nt) {
                const int l = i ^ j;
                if (l > i) {
                    const float vi = vals[i], vl = vals[l];
                    const int   ii = idxs[i], il = idxs[l];
                    const bool up = (i & k) == 0;
                    const bool sw = up ? first_pair(vl, il, vi, ii)
                                       : first_pair(vi, ii, vl, il);
                    if (sw) { vals[i] = vl; vals[l] = vi; idxs[i] = il; idxs[l] = ii; }
                }
            }
        }
    }
    __syncthreads();
}

// ---------------------------------------------------------------------------
// Pass A (MFMA): swapped QK^T -> per-lane logits for 16 s-cols (s = lane&15),
// t = nt*16 + quad*4 + r. 4-product split bf16 QK (fp32-level accuracy; the
// logits feed the top-k masks, which must not flip). Softmax over t = register
// max/sum + shfl_xor(16/32) quad reduce. Accumulate sum_s p per t -> tokp.
// Grid: 2560 blocks = b(8) x h(20) x s-chunk(16); 4 waves x 4 s-tiles = 256 s.
// ---------------------------------------------------------------------------
__global__ __launch_bounds__(256)
void pass_a_kernel(const float* __restrict__ q, const float* __restrict__ kbuf,
                   float* __restrict__ tokp)
{
    __shared__ unsigned short khi[80 * 64];   // [t][d] bf16, XOR-swizzled rows
    __shared__ unsigned short klo[80 * 64];
    __shared__ float wsum[4][80];
    const int g = blockIdx.x;
    const int b = g / 320;
    const int rem = g % 320;
    const int h = rem >> 4;
    const int chunk = rem & 15;
    const int tid = threadIdx.x;

    // stage K slice -> swizzled bf16 hi/lo (T2 swizzle: byte ^= (t&7)<<4)
    for (int i = tid; i < 80 * 16; i += 256) {
        const int t = i >> 4, j = i & 15;                 // d0 = 4*j
        float4 v = make_float4(0.f, 0.f, 0.f, 0.f);
        if (t < T_) v = *(const float4*)(kbuf + (size_t)(b * T_ + t) * HD_ + h * D_ + 4 * j);
        ushort4 hh, ll;
        hh.x = f2bf(v.x); ll.x = f2bf(v.x - bf2f(hh.x));
        hh.y = f2bf(v.y); ll.y = f2bf(v.y - bf2f(hh.y));
        hh.z = f2bf(v.z); ll.z = f2bf(v.z - bf2f(hh.z));
        hh.w = f2bf(v.w); ll.w = f2bf(v.w - bf2f(hh.w));
        const int byt = t * 128 + ((8 * j) ^ ((t & 7) << 4));
        *(ushort4*)((char*)khi + byt) = hh;
        *(ushort4*)((char*)klo + byt) = ll;
    }
    __syncthreads();

    const int wid = tid >> 6, lane = tid & 63;
    const int lrow = lane & 15, quad = lane >> 4;

    f32x4 tokacc[5] = {};
    for (int st = 0; st < 4; ++st) {
        const int s = chunk * 256 + wid * 64 + st * 16 + lrow;
        const float* qp = q + (size_t)(b * S_ + s) * HD_ + h * D_;
        bf16x8 qhi[2], qlo[2];
        #pragma unroll
        for (int ks = 0; ks < 2; ++ks)
            split_frag(qp + ks * 32 + quad * 8, qhi[ks], qlo[ks]);

        f32x4 acc[5] = {};
        #pragma unroll
        for (int nt = 0; nt < 5; ++nt) {
            #pragma unroll
            for (int ks = 0; ks < 2; ++ks) {
                const int krow = nt * 16 + lrow;
                const int byt = krow * 128 + ((64 * ks + 16 * quad) ^ ((krow & 7) << 4));
                const bf16x8 kh = *(const bf16x8*)((const char*)khi + byt);
                const bf16x8 kl = *(const bf16x8*)((const char*)klo + byt);
                acc[nt] = MFMA16(kh, qhi[ks], acc[nt], 0, 0, 0);
                acc[nt] = MFMA16(kh, qlo[ks], acc[nt], 0, 0, 0);
                acc[nt] = MFMA16(kl, qhi[ks], acc[nt], 0, 0, 0);
                acc[nt] = MFMA16(kl, qlo[ks], acc[nt], 0, 0, 0);
            }
        }
        float m = -1e30f;
        #pragma unroll
        for (int nt = 0; nt < 5; ++nt)
            #pragma unroll
            for (int r = 0; r < 4; ++r) {
                const int t = nt * 16 + quad * 4 + r;
                const float l = (t < T_) ? acc[nt][r] * SCALE_ : -1e30f;
                acc[nt][r] = l;
                m = fmaxf(m, l);
            }
        m = fmaxf(m, __shfl_xor(m, 16, 64));
        m = fmaxf(m, __shfl_xor(m, 32, 64));
        float Lp = 0.f;
        #pragma unroll
        for (int nt = 0; nt < 5; ++nt)
            #pragma unroll
            for (int r = 0; r < 4; ++r) {
                const float e = __expf(acc[nt][r] - m);
                acc[nt][r] = e;
                Lp += e;
            }
        float L = Lp + __shfl_xor(Lp, 16, 64);
        L += __shfl_xor(L, 32, 64);
        const float invL = 1.0f / L;
        #pragma unroll
        for (int nt = 0; nt < 5; ++nt)
            #pragma unroll
            for (int r = 0; r < 4; ++r)
                tokacc[nt][r] = fmaf(acc[nt][r], invL, tokacc[nt][r]);
    }
    // reduce over the 16 s-columns (lane bits 0..3), write per-wave partials
    #pragma unroll
    for (int nt = 0; nt < 5; ++nt)
        #pragma unroll
        for (int r = 0; r < 4; ++r) {
            float v = tokacc[nt][r];
            v += __shfl_xor(v, 1, 64);
            v += __shfl_xor(v, 2, 64);
            v += __shfl_xor(v, 4, 64);
            v += __shfl_xor(v, 8, 64);
            if (lrow == 0) wsum[wid][nt * 16 + quad * 4 + r] = v;
        }
    __syncthreads();
    for (int t = tid; t < T_; t += 256)
        tokp[(size_t)g * T_ + t] = (wsum[0][t] + wsum[1][t]) + (wsum[2][t] + wsum[3][t]);
}

// ---------------------------------------------------------------------------
// Top-k over 77 token scores per batch -> tok_mask. 8 blocks x 128 threads.
// ---------------------------------------------------------------------------
__global__ __launch_bounds__(128)
void topk_tok_kernel(const float* __restrict__ tokp, float* __restrict__ tokm)
{
    __shared__ float vals[128];
    __shared__ int idxs[128];
    const int b = blockIdx.x, tid = threadIdx.x;
    float v = -1e30f;
    if (tid < T_) {
        float sm = 0.f;
        for (int j = 0; j < 320; ++j) sm += tokp[(size_t)(b * 320 + j) * T_ + tid];
        v = sm;
    }
    vals[tid] = v; idxs[tid] = tid;
    bitonic_desc(vals, idxs, 128, tid, 128);
    if (tid < T_) tokm[b * T_ + tid] = 0.f;
    __syncthreads();
    if (tid < KTOK_) tokm[b * T_ + idxs[tid]] = 1.0f;
}

// ---------------------------------------------------------------------------
// K/V cross-frame mixing: kd = k2-k (delta, mask folded in), v2 = mixed v.
// ---------------------------------------------------------------------------
__global__ __launch_bounds__(256)
void mix_kernel(const float* __restrict__ kbuf, const float* __restrict__ vbuf,
                const float* __restrict__ tokm,
                float* __restrict__ kd, float* __restrict__ v2)
{
    const int i = blockIdx.x * 256 + threadIdx.x;   // < 77*1280 = 98560
    const int t = i / HD_;
    float ks = 0.f, vs = 0.f;
    #pragma unroll
    for (int b = 0; b < B_; ++b) {
        ks += kbuf[(size_t)b * T_ * HD_ + i];
        vs += vbuf[(size_t)b * T_ * HD_ + i];
    }
    #pragma unroll
    for (int b = 0; b < B_; ++b) {
        const size_t gi = (size_t)b * T_ * HD_ + i;
        const float msk = tokm[b * T_ + t];
        const float kx = kbuf[gi], vx = vbuf[gi];
        kd[gi] = CMIX_ * msk * ((ks - 8.f * kx) * (1.0f / 7.0f));
        v2[gi] = vx + CMIX_ * msk * ((vs - 8.f * vx) * (1.0f / 7.0f));
    }
}

// ---------------------------------------------------------------------------
// Fused pass B+C (MFMA): swapped QK^T gives per-lane l1 (split, 4 products)
// and l2 = l1 + q·kd (kd bf16-hi; mask folded into kd). Register softmax for
// both; posp = masked mass of softmax(l1); p2 = softmax(l2) -> LDS round-trip
// per 32-wide k-step (hi/lo) -> swapped PV mfma(V^T, P) -> ctx.
// ---------------------------------------------------------------------------
__global__ __launch_bounds__(256)
void pass_bc_kernel(const float* __restrict__ q, const float* __restrict__ kbuf,
                    const float* __restrict__ kd, const float* __restrict__ v2,
                    const float* __restrict__ tokm,
                    float* __restrict__ posp, float* __restrict__ ctx)
{
    __shared__ unsigned short khi[80 * 64];     // [t][d] XOR-swizzled
    __shared__ unsigned short klo[80 * 64];
    __shared__ unsigned short kdh[80 * 64];
    __shared__ unsigned short vThi[64 * 88];    // [d][t] rows padded to 88
    __shared__ unsigned short vTlo[64 * 88];
    __shared__ unsigned short vguard[128];      // zeroed guard for vT overreads
    __shared__ unsigned short Pbuf[4][2][16 * 40]; // per-wave [hi/lo][s][tloc]
    __shared__ float smaskf[80];

    const int g = blockIdx.x;
    const int b = g / 320;
    const int rem = g % 320;
    const int h = rem >> 4;
    const int chunk = rem & 15;
    const int tid = threadIdx.x;

    // ---- stage K (hi/lo) + Kd (hi), swizzled ----
    for (int i = tid; i < 80 * 16; i += 256) {
        const int t = i >> 4, j = i & 15;
        float4 vk = make_float4(0.f, 0.f, 0.f, 0.f);
        float4 vd = make_float4(0.f, 0.f, 0.f, 0.f);
        if (t < T_) {
            const size_t gi = (size_t)(b * T_ + t) * HD_ + h * D_ + 4 * j;
            vk = *(const float4*)(kbuf + gi);
            vd = *(const float4*)(kd + gi);
        }
        ushort4 hh, ll, dd;
        hh.x = f2bf(vk.x); ll.x = f2bf(vk.x - bf2f(hh.x)); dd.x = f2bf(vd.x);
        hh.y = f2bf(vk.y); ll.y = f2bf(vk.y - bf2f(hh.y)); dd.y = f2bf(vd.y);
        hh.z = f2bf(vk.z); ll.z = f2bf(vk.z - bf2f(hh.z)); dd.z = f2bf(vd.z);
        hh.w = f2bf(vk.w); ll.w = f2bf(vk.w - bf2f(hh.w)); dd.w = f2bf(vd.w);
        const int byt = t * 128 + ((8 * j) ^ ((t & 7) << 4));
        *(ushort4*)((char*)khi + byt) = hh;
        *(ushort4*)((char*)klo + byt) = ll;
        *(ushort4*)((char*)kdh + byt) = dd;
    }
    // ---- stage V^T (hi/lo): rows d (88 cols, zero-padded past t=76) ----
    for (int i = tid; i < 64 * 22; i += 256) {
        const int d = i / 22, jg = i - d * 22;           // cols t = 4*jg..+3
        float vv[4];
        #pragma unroll
        for (int r = 0; r < 4; ++r) {
            const int t = 4 * jg + r;
            vv[r] = (t < T_) ? v2[(size_t)(b * T_ + t) * HD_ + h * D_ + d] : 0.f;
        }
        ushort4 hh, ll;
        hh.x = f2bf(vv[0]); ll.x = f2bf(vv[0] - bf2f(hh.x));
        hh.y = f2bf(vv[1]); ll.y = f2bf(vv[1] - bf2f(hh.y));
        hh.z = f2bf(vv[2]); ll.z = f2bf(vv[2] - bf2f(hh.z));
        hh.w = f2bf(vv[3]); ll.w = f2bf(vv[3] - bf2f(hh.w));
        const int byt = d * 176 + 8 * jg;
        *(ushort4*)((char*)vThi + byt) = hh;
        *(ushort4*)((char*)vTlo + byt) = ll;
    }
    for (int t = tid; t < 80; t += 256) smaskf[t] = (t < T_) ? tokm[b * T_ + t] : 0.f;
    for (int i = tid; i < 128; i += 256) vguard[i] = 0;
    __syncthreads();

    const int wid = tid >> 6, lane = tid & 63;
    const int lrow = lane & 15, quad = lane >> 4;
    unsigned short* Ph = &Pbuf[wid][0][0];
    unsigned short* Pl = &Pbuf[wid][1][0];

    // hoist per-lane token-mask values (constant across s-tiles)
    float smv[5][4];
    #pragma unroll
    for (int nt = 0; nt < 5; ++nt)
        #pragma unroll
        for (int r = 0; r < 4; ++r)
            smv[nt][r] = smaskf[nt * 16 + quad * 4 + r];

    for (int st = 0; st < 4; ++st) {
        const int s = chunk * 256 + wid * 64 + st * 16 + lrow;
        const float* qp = q + (size_t)(b * S_ + s) * HD_ + h * D_;
        bf16x8 qhi[2], qlo[2];
        #pragma unroll
        for (int ks = 0; ks < 2; ++ks)
            split_frag(qp + ks * 32 + quad * 8, qhi[ks], qlo[ks]);

        f32x4 acc1[5] = {}, accd[5] = {};
        #pragma unroll
        for (int nt = 0; nt < 5; ++nt) {
            #pragma unroll
            for (int ks = 0; ks < 2; ++ks) {
                const int krow = nt * 16 + lrow;
                const int byt = krow * 128 + ((64 * ks + 16 * quad) ^ ((krow & 7) << 4));
                const bf16x8 kh = *(const bf16x8*)((const char*)khi + byt);
                const bf16x8 kl = *(const bf16x8*)((const char*)klo + byt);
                const bf16x8 kdv = *(const bf16x8*)((const char*)kdh + byt);
                acc1[nt] = MFMA16(kh, qhi[ks], acc1[nt], 0, 0, 0);
                acc1[nt] = MFMA16(kh, qlo[ks], acc1[nt], 0, 0, 0);
                acc1[nt] = MFMA16(kl, qhi[ks], acc1[nt], 0, 0, 0);
                acc1[nt] = MFMA16(kl, qlo[ks], acc1[nt], 0, 0, 0);
                accd[nt] = MFMA16(kdv, qhi[ks], accd[nt], 0, 0, 0);
            }
        }

        // logits + dual softmax (l1: pos score; l2: second attention)
        float m1 = -1e30f, m2 = -1e30f;
        f32x4 l2v[5];
        #pragma unroll
        for (int nt = 0; nt < 5; ++nt)
            #pragma unroll
            for (int r = 0; r < 4; ++r) {
                const int t = nt * 16 + quad * 4 + r;
                const bool valid = t < T_;
                const float l1 = valid ? acc1[nt][r] * SCALE_ : -1e30f;
                const float l2 = valid ? l1 + accd[nt][r] * SCALE_ : -1e30f;
                acc1[nt][r] = l1;
                l2v[nt][r] = l2;
                m1 = fmaxf(m1, l1);
                m2 = fmaxf(m2, l2);
            }
        m1 = fmaxf(m1, __shfl_xor(m1, 16, 64));
        m1 = fmaxf(m1, __shfl_xor(m1, 32, 64));
        m2 = fmaxf(m2, __shfl_xor(m2, 16, 64));
        m2 = fmaxf(m2, __shfl_xor(m2, 32, 64));
        float L1p = 0.f, Smp = 0.f, L2p = 0.f;
        #pragma unroll
        for (int nt = 0; nt < 5; ++nt)
            #pragma unroll
            for (int r = 0; r < 4; ++r) {
                const float e1 = __expf(acc1[nt][r] - m1);
                L1p += e1;
                Smp = fmaf(e1, smv[nt][r], Smp);
                const float e2 = __expf(l2v[nt][r] - m2);
                l2v[nt][r] = e2;
                L2p += e2;
            }
        float L1 = L1p + __shfl_xor(L1p, 16, 64); L1 += __shfl_xor(L1, 32, 64);
        float Sm = Smp + __shfl_xor(Smp, 16, 64); Sm += __shfl_xor(Sm, 32, 64);
        float L2 = L2p + __shfl_xor(L2p, 16, 64); L2 += __shfl_xor(L2, 32, 64);
        if (quad == 0) posp[(size_t)(b * H_ + h) * S_ + s] = Sm / L1;
        const float invL2 = 1.0f / L2;
        #pragma unroll
        for (int nt = 0; nt < 5; ++nt)
            #pragma unroll
            for (int r = 0; r < 4; ++r)
                l2v[nt][r] *= invL2;

        // PV: per 32-wide k-step, P -> LDS (hi/lo) -> B-frags, V^T A-frags
        f32x4 pv[4] = {};
        #pragma unroll
        for (int ks = 0; ks < 3; ++ks) {
            asm volatile("s_waitcnt lgkmcnt(0)" ::: "memory");
            __builtin_amdgcn_sched_barrier(0);
            #pragma unroll
            for (int half = 0; half < 2; ++half) {
                const int nt = 2 * ks + half;
                ushort4 ph = {0, 0, 0, 0}, plw = {0, 0, 0, 0};
                if (nt < 5) {
                    ph.x = f2bf(l2v[nt][0]); plw.x = f2bf(l2v[nt][0] - bf2f(ph.x));
                    ph.y = f2bf(l2v[nt][1]); plw.y = f2bf(l2v[nt][1] - bf2f(ph.y));
                    ph.z = f2bf(l2v[nt][2]); plw.z = f2bf(l2v[nt][2] - bf2f(ph.z));
                    ph.w = f2bf(l2v[nt][3]); plw.w = f2bf(l2v[nt][3] - bf2f(ph.w));
                }
                const int pb = lrow * 80 + 32 * half + 8 * quad;
                *(ushort4*)((char*)Ph + pb) = ph;
                *(ushort4*)((char*)Pl + pb) = plw;
            }
            asm volatile("s_waitcnt lgkmcnt(0)" ::: "memory");
            __builtin_amdgcn_sched_barrier(0);
            const bf16x8 pH = *(const bf16x8*)((const char*)Ph + lrow * 80 + quad * 16);
            const bf16x8 pL = *(const bf16x8*)((const char*)Pl + lrow * 80 + quad * 16);
            #pragma unroll
            for (int mt = 0; mt < 4; ++mt) {
                const int vb = (mt * 16 + lrow) * 176 + 64 * ks + 16 * quad;
                const bf16x8 vH = *(const bf16x8*)((const char*)vThi + vb);
                const bf16x8 vL = *(const bf16x8*)((const char*)vTlo + vb);
                pv[mt] = MFMA16(vH, pH, pv[mt], 0, 0, 0);
                pv[mt] = MFMA16(vH, pL, pv[mt], 0, 0, 0);
                pv[mt] = MFMA16(vL, pH, pv[mt], 0, 0, 0);
            }
        }
        // ctx write: col = lane&15 = s, row(d) = mt*16 + quad*4 + reg
        float* cp = ctx + (size_t)(b * S_ + s) * HD_ + h * D_;
        #pragma unroll
        for (int mt = 0; mt < 4; ++mt) {
            const float4 o = make_float4(pv[mt][0], pv[mt][1], pv[mt][2], pv[mt][3]);
            *(float4*)(cp + mt * 16 + quad * 4) = o;
        }
    }
}

// ---------------------------------------------------------------------------
// Top-k over 4096 position scores per batch -> pos_mask. 8 blocks x 1024.
// ---------------------------------------------------------------------------
__global__ __launch_bounds__(1024)
void topk_pos_kernel(const float* __restrict__ posp, float* __restrict__ posm)
{
    __shared__ float vals[S_];
    __shared__ int idxs[S_];
    const int b = blockIdx.x, tid = threadIdx.x;
    for (int s = tid; s < S_; s += 1024) {
        float sm = 0.f;
        for (int h = 0; h < H_; ++h) sm += posp[(size_t)(b * H_ + h) * S_ + s];
        vals[s] = sm; idxs[s] = s;
    }
    bitonic_desc(vals, idxs, S_, tid, 1024);
    for (int s = tid; s < S_; s += 1024) posm[b * S_ + s] = 0.f;
    __syncthreads();
    for (int i = tid; i < KPOS_; i += 1024) posm[b * S_ + idxs[i]] = 1.0f;
}

// ---------------------------------------------------------------------------
// Batch-sum of context over b: csum[s,hd] = sum_b ctx[b,s,hd]. float4 lanes.
// ---------------------------------------------------------------------------
__global__ __launch_bounds__(256)
void ctxsum_kernel(const float* __restrict__ ctx, float* __restrict__ csum)
{
    const size_t i = (size_t)blockIdx.x * 256 + threadIdx.x;  // float4 index
    const float4* c = (const float4*)ctx;
    float4 a = c[i];
    #pragma unroll
    for (int b = 1; b < B_; ++b) {
        const float4 x = c[(size_t)b * (S_ * HD_ / 4) + i];
        a.x += x.x; a.y += x.y; a.z += x.z; a.w += x.w;
    }
    ((float4*)csum)[i] = a;
}

// ---------------------------------------------------------------------------
extern "C" void kernel_launch(void* const* d_in, const int* in_sizes, int n_in,
                              void* d_out, int out_size, void* d_ws, size_t ws_size,
                              hipStream_t stream)
{
    const float* hidden = (const float*)d_in[0];
    const float* enc    = (const float*)d_in[1];
    const float* Wq     = (const float*)d_in[2];
    const float* Wk     = (const float*)d_in[3];
    const float* Wv     = (const float*)d_in[4];
    const float* Wo     = (const float*)d_in[5];
    const float* bo     = (const float*)d_in[6];
    float* out = (float*)d_out;

    char* w = (char*)d_ws;
    float* q    = (float*)w; w += (size_t)M1_ * HD_ * 4;
    float* ctx  = (float*)w; w += (size_t)M1_ * HD_ * 4;
    float* kbuf = (float*)w; w += (size_t)B_ * T_ * HD_ * 4;
    float* vbuf = (float*)w; w += (size_t)B_ * T_ * HD_ * 4;
    float* kd   = (float*)w; w += (size_t)B_ * T_ * HD_ * 4;
    float* v2   = (float*)w; w += (size_t)B_ * T_ * HD_ * 4;
    float* csum = (float*)w; w += (size_t)S_ * HD_ * 4;
    float* tokp = (float*)w; w += (size_t)2560 * T_ * 4;
    float* posp = (float*)w; w += (size_t)B_ * H_ * S_ * 4;
    float* tokm = (float*)w; w += (size_t)B_ * T_ * 4;
    float* posm = (float*)w; w += (size_t)B_ * S_ * 4;
    unsigned short* Ahi   = (unsigned short*)w; w += (size_t)M1_ * HD_ * 2;
    unsigned short* Alo   = (unsigned short*)w; w += (size_t)M1_ * HD_ * 2;
    unsigned short* ctxb  = (unsigned short*)w; w += (size_t)M1_ * HD_ * 2;
    unsigned short* WqhiT = (unsigned short*)w; w += (size_t)C_ * HD_ * 2;
    unsigned short* WqloT = (unsigned short*)w; w += (size_t)C_ * HD_ * 2;
    unsigned short* WohiT = (unsigned short*)w; w += (size_t)HD_ * C_ * 2;
    unsigned short* WoloT = (unsigned short*)w; w += (size_t)HD_ * C_ * 2;
    (void)ws_size; (void)in_sizes; (void)n_in; (void)out_size;

    // 1. Split hidden -> bf16 hi/lo; weights -> transposed bf16 hi/lo
    split_convert_kernel<<<M1_ * HD_ / 4 / 256, 256, 0, stream>>>(hidden, Ahi, Alo);
    wsplitT_kernel<<<dim3(40, 40), 256, 0, stream>>>(Wq, WqhiT, WqloT);
    wsplitT_kernel<<<dim3(40, 40), 256, 0, stream>>>(Wo, WohiT, WoloT);
    // 2. Q projection: split-bf16 MFMA (3 products ~ fp32 accuracy)
    mfma_gemm_kernel<true, false><<<2560, 256, 0, stream>>>(
        Ahi, Alo, WqhiT, WqloT, q, C_, nullptr, nullptr);
    // 3. K and V projections (fp32 — feeds scoring path)
    gemm64_kernel<<<dim3(20, 10, 2), 256, 0, stream>>>(
        enc, Wk, Wv, kbuf, vbuf, MKV_, HD_, CENC_);
    // 4. First attention (MFMA) -> token-score partials
    pass_a_kernel<<<2560, 256, 0, stream>>>(q, kbuf, tokp);
    // 5. Token top-k mask
    topk_tok_kernel<<<8, 128, 0, stream>>>(tokp, tokm);
    // 6. Cross-frame K/V mixing
    mix_kernel<<<385, 256, 0, stream>>>(kbuf, vbuf, tokm, kd, v2);
    // 7. Fused pass B (pos scores) + pass C (second attention, MFMA)
    pass_bc_kernel<<<2560, 256, 0, stream>>>(q, kbuf, kd, v2, tokm, posp, ctx);
    // 8. Position top-k mask
    topk_pos_kernel<<<8, 1024, 0, stream>>>(posp, posm);
    // 9. Batch-sum of context for mean-of-others injection
    ctxsum_kernel<<<S_ * HD_ / 4 / 256, 256, 0, stream>>>(ctx, csum);
    // 10. Injection + bf16 convert of context (A operand of O-proj)
    inject_convert_kernel<<<M1_ * HD_ / 4 / 256, 256, 0, stream>>>(ctx, csum, posm, ctxb);
    // 11. O projection: plain bf16 MFMA + bias + residual epilogue
    mfma_gemm_kernel<false, true><<<2560, 256, 0, stream>>>(
        ctxb, nullptr, WohiT, nullptr, out, HD_, bo, hidden);
}